// Round 5
// baseline (1254.871 us; speedup 1.0000x reference)
//
#include <hip/hip_runtime.h>
#include <cstdint>
#include <cstddef>

// RNNQNetwork: MLP encoder (bf16 MFMA GEMMs) -> 128-step GRU scan
// (weight-stationary distributed GEMM, cross-block handoff via per-access
// coherent sc0/sc1 ops + per-step fresh h buffer) -> output head GEMM.
//
// R9: non-gru time is a constant ~722us across all rounds (GEMMs at
// short-K 2-barrier structure = few hundred TF; GEMM1+2+gin ~= 170 GFLOP
// dominates). This round: BK 32->64 in k_gemm_bt/k_qout - halves barrier
// iterations (16->8) and makes each 128B A/B line fully consumed within
// one staging window (BK=32 used half a line/iter). LDS 16->32KB per
// GEMM block (multi-block/CU retained; 64KB was the known regression).
// k_gru untouched (verified 517us: IC-handoff chain ~1.3us/step + h-read
// amplification ~0.5-1us/step is near that design's floor).

#define TT 128
#define BBATCH 512
#define HH 512
#define MM 65536   // T*B
#define AD 18
#define GSTEPS 8   // gin staging chunk (steps per LDS buffer)
#define FSTRIDE 32 // u32s between flags (128B: one line per flag)
#define READY_U32 1064960  // ((8*130)*32) flags * FSTRIDE

typedef __attribute__((ext_vector_type(8))) short short8;
typedef __attribute__((ext_vector_type(4))) float float4v;
typedef __attribute__((ext_vector_type(4))) unsigned int uint4v;

__device__ __forceinline__ unsigned short f2bf(float f) {
  union { float f; unsigned int u; } v; v.f = f;
  unsigned int r = v.u + 0x7fffu + ((v.u >> 16) & 1u);  // RNE
  return (unsigned short)(r >> 16);
}
__device__ __forceinline__ float bf2f(unsigned short h) {
  union { unsigned int u; float f; } v; v.u = ((unsigned int)h) << 16;
  return v.f;
}

// per-access coherent (coherence-point) ops: sc0 sc1 = device-scope, no fence
__device__ __forceinline__ unsigned int load_u32_coh(const unsigned int* p) {
  unsigned int v;
  asm volatile("global_load_dword %0, %1, off sc0 sc1\n\ts_waitcnt vmcnt(0)"
               : "=v"(v) : "v"(p) : "memory");
  return v;
}
__device__ __forceinline__ void store_u32_coh(unsigned int* p, unsigned int v) {
  asm volatile("global_store_dword %0, %1, off sc0 sc1"
               :: "v"(p), "v"(v) : "memory");
}
__device__ __forceinline__ void store_u64_coh(void* p, unsigned long long v) {
  asm volatile("global_store_dwordx2 %0, %1, off sc0 sc1"
               :: "v"(p), "v"(v) : "memory");
}

// async global->LDS, 16B per lane. LDS dest must be wave-uniform base;
// lanes deposit at base + lane*16 (guide section 5 caveat).
typedef __attribute__((address_space(3))) unsigned int* lds_u32p;
typedef const __attribute__((address_space(1))) unsigned int* glb_u32p;
__device__ __forceinline__ void async16(void* lds, const void* g) {
  __builtin_amdgcn_global_load_lds(
      (glb_u32p)(unsigned long long)g,
      (lds_u32p)(unsigned int)(unsigned long long)lds, 16, 0, 0);
}

// ---------------- prep kernels ----------------

// obs fp32 -> bf16 (packed 4/thread); also zero the dones-format flag.
__global__ __launch_bounds__(256) void k_conv_obs(
    const float* __restrict__ src, unsigned short* __restrict__ dst,
    unsigned int* __restrict__ flag) {
  if (blockIdx.x == 0 && threadIdx.x == 0) *flag = 0u;
  int i = blockIdx.x * 256 + threadIdx.x;      // grid sized exactly
  float4v v = ((const float4v*)src)[i];
  unsigned long long pk = (unsigned long long)f2bf(v[0])
      | ((unsigned long long)f2bf(v[1]) << 16)
      | ((unsigned long long)f2bf(v[2]) << 32)
      | ((unsigned long long)f2bf(v[3]) << 48);
  ((unsigned long long*)dst)[i] = pk;
}

// Transpose [512][512] fp32 weights -> [N][K] bf16 (B^T layout for gemm_bt).
__global__ __launch_bounds__(256) void k_prep_t(
    const float* __restrict__ w0, const float* __restrict__ w1,
    const float* __restrict__ wir, const float* __restrict__ wiz,
    const float* __restrict__ win,
    unsigned short* __restrict__ W0at, unsigned short* __restrict__ W1t,
    unsigned short* __restrict__ Wit) {
  int o = blockIdx.x * 256 + threadIdx.x;  // o = n*512 + k
  int n = o >> 9, k = o & 511;
  int z = blockIdx.y;
  const float* s = (z == 0) ? w0 : (z == 1) ? w1 : (z == 2) ? wir
                 : (z == 3) ? wiz : win;
  unsigned short b = f2bf(s[k * 512 + n]);
  if (z == 0) W0at[o] = b;
  else if (z == 1) W1t[o] = b;
  else Wit[(size_t)(z - 2) * 262144 + o] = b;
}

// Hidden weights [w_hr|w_hz|w_hn] -> MFMA-fragment layout:
// Whf unit (k>>3)*1536 + n holds bf16 W[k0..k0+8][n] contiguously (16B).
__global__ __launch_bounds__(256) void k_prep_whf(
    const float* __restrict__ whr, const float* __restrict__ whz,
    const float* __restrict__ whn, unsigned short* __restrict__ Whf) {
  int i = blockIdx.x * 256 + threadIdx.x;  // < 512*1536, grid exact
  int k = i / 1536, n = i - k * 1536;
  const float* s = (n < 512) ? whr : (n < 1024) ? whz : whn;
  float v = s[k * 512 + (n & 511)];
  Whf[((size_t)(k >> 3) * 1536 + n) * 8 + (k & 7)] = f2bf(v);
}

// Misc: w0 action rows (bf16), combined gru-input bias, w_out^T padded to 64,
// initial h (bf16), detect dones dtype.
__global__ __launch_bounds__(256) void k_prep_misc(
    const float* __restrict__ w0, const float* __restrict__ bir,
    const float* __restrict__ biz, const float* __restrict__ bin,
    const float* __restrict__ wout, const float* __restrict__ hidden,
    const int* __restrict__ dI,
    unsigned short* __restrict__ w0act, float* __restrict__ gib,
    unsigned short* __restrict__ WoutT, unsigned short* __restrict__ hbuf,
    unsigned int* __restrict__ flag) {
  int i = blockIdx.x * 256 + threadIdx.x;  // grid 1024 -> i < 262144
  if (i < 9216) {
    int a = i >> 9, n = i & 511;
    w0act[i] = f2bf(w0[(512 + a) * 512 + n]);
  }
  if (i < 1536)
    gib[i] = (i < 512) ? bir[i] : (i < 1024) ? biz[i - 512] : bin[i - 1024];
  if (i < 32768) {
    int n = i >> 9, k = i & 511;
    WoutT[i] = f2bf(n < AD ? wout[k * AD + n] : 0.f);
  }
  if (i < 262144) hbuf[i] = f2bf(hidden[i]);
  // dones dtype probe: first 64KB viewed as int32. int32 bools are only
  // {0,1}; packed byte-bools produce values with bits above bit0.
  if (i < 16384) { if (dI[i] & 0xFFFFFFFE) atomicOr(flag, 1u); }
}

// zero the spread flag array (lives in bufA, dead after the gin GEMM)
__global__ __launch_bounds__(256) void k_zero(unsigned int* __restrict__ p) {
  int i = (blockIdx.x * 256 + threadIdx.x) * 4;
  if (i < READY_U32) *(uint4v*)(p + i) = (uint4v){0u, 0u, 0u, 0u};
}

// ---------------- phase A: GEMM C = A @ B^T (+bias [+one-hot gather]) ------
// BK=64: 8 k-iterations, 2x16 MFMA per iteration, full 128B-line staging.
// MODE 0: plain C[row][col]. MODE 1: + gathered w0 action row (GEMM1).
// MODE 2: gin scan-blocked epilogue: dst[(b>>6)*32 + (c&511)>>4][t][g][b&63][c&15]

template <int MODE>
__global__ __launch_bounds__(256) void k_gemm_bt(
    const unsigned short* __restrict__ Ab,   // [M][512] bf16
    const unsigned short* __restrict__ Btb,  // [N][512] bf16
    unsigned short* __restrict__ Cb,         // [M][Ndim] bf16 (or blocked)
    int Ndim, const float* __restrict__ bias,
    const unsigned short* __restrict__ gW,   // [18][512] bf16
    const int* __restrict__ acts) {
  // chunk-major: unit u = ch*128 + row, ch = k-octet 0..7, 16B per unit
  __shared__ unsigned short As[8192];
  __shared__ unsigned short Bs[8192];
  const int tid = threadIdx.x, wave = tid >> 6, lane = tid & 63;
  const int quad = lane >> 4, l15 = lane & 15;
  const int m0 = blockIdx.x * 128, n0 = blockIdx.y * 128;
  const int mblk = (wave & 1) * 64, nblk = (wave >> 1) * 64;

  float4v acc[4][4];
#pragma unroll
  for (int a = 0; a < 4; ++a)
#pragma unroll
    for (int b = 0; b < 4; ++b) acc[a][b] = (float4v){0.f, 0.f, 0.f, 0.f};

  for (int k0 = 0; k0 < 512; k0 += 64) {
#pragma unroll
    for (int r = 0; r < 4; ++r) {
      int u = r * 256 + wave * 64 + lane;
      int ch = u >> 7, mm = u & 127;
      async16(&As[(size_t)(r * 256 + wave * 64) * 8],
              Ab + (size_t)(m0 + mm) * 512 + k0 + ch * 8);
      async16(&Bs[(size_t)(r * 256 + wave * 64) * 8],
              Btb + (size_t)(n0 + mm) * 512 + k0 + ch * 8);
    }
    __syncthreads();  // compiler drains vmcnt before s_barrier
#pragma unroll
    for (int kk = 0; kk < 2; ++kk) {
      short8 afr[4], bfr[4];
#pragma unroll
      for (int mi = 0; mi < 4; ++mi)
        afr[mi] = *(const short8*)
            &As[((kk * 4 + quad) * 128 + mblk + mi * 16 + l15) * 8];
#pragma unroll
      for (int ni = 0; ni < 4; ++ni)
        bfr[ni] = *(const short8*)
            &Bs[((kk * 4 + quad) * 128 + nblk + ni * 16 + l15) * 8];
#pragma unroll
      for (int mi = 0; mi < 4; ++mi)
#pragma unroll
        for (int ni = 0; ni < 4; ++ni)
          acc[mi][ni] = __builtin_amdgcn_mfma_f32_16x16x32_bf16(
              afr[mi], bfr[ni], acc[mi][ni], 0, 0, 0);
    }
    __syncthreads();
  }

#pragma unroll
  for (int mi = 0; mi < 4; ++mi) {
#pragma unroll
    for (int i = 0; i < 4; ++i) {
      int row = m0 + mblk + mi * 16 + quad * 4 + i;
      int arow = (MODE == 1) ? acts[row] : 0;
#pragma unroll
      for (int ni = 0; ni < 4; ++ni) {
        int col = n0 + nblk + ni * 16 + l15;
        float v = acc[mi][ni][i] + bias[col];
        if (MODE == 1) v += bf2f(gW[arow * 512 + col]);
        if (MODE == 2) {
          int t = row >> 9, b = row & 511;
          int c = col & 511;
          size_t dst = ((size_t)((b >> 6) * 32 + (c >> 4)) * 128 + t) * 3072
                     + (size_t)(col >> 9) * 1024 + (b & 63) * 16 + (c & 15);
          Cb[dst] = f2bf(v);
        } else {
          Cb[(size_t)row * Ndim + col] = f2bf(v);
        }
      }
    }
  }
}

// ---------------- LayerNorm(+bias already applied) + ReLU, bf16->bf16 -------

__global__ __launch_bounds__(256) void k_ln_relu(
    const unsigned short* __restrict__ X, unsigned short* __restrict__ Y,
    const float* __restrict__ sc, const float* __restrict__ bi) {
  int row = blockIdx.x * 4 + (threadIdx.x >> 6);  // one wave per row
  int lane = threadIdx.x & 63;
  uint4v u = *(const uint4v*)(X + (size_t)row * 512 + lane * 8);
  float v[8];
#pragma unroll
  for (int j = 0; j < 4; ++j) {
    v[2 * j] = bf2f((unsigned short)(u[j] & 0xffffu));
    v[2 * j + 1] = bf2f((unsigned short)(u[j] >> 16));
  }
  float s = 0.f, q = 0.f;
#pragma unroll
  for (int j = 0; j < 8; ++j) { s += v[j]; q += v[j] * v[j]; }
#pragma unroll
  for (int d = 1; d < 64; d <<= 1) {
    s += __shfl_xor(s, d, 64);
    q += __shfl_xor(q, d, 64);
  }
  float mean = s * (1.f / 512.f);
  float var = fmaxf(q * (1.f / 512.f) - mean * mean, 0.f);
  float rstd = rsqrtf(var + 1e-6f);
  float4v s0 = *(const float4v*)(sc + lane * 8);
  float4v s1 = *(const float4v*)(sc + lane * 8 + 4);
  float4v c0 = *(const float4v*)(bi + lane * 8);
  float4v c1 = *(const float4v*)(bi + lane * 8 + 4);
  uint4v w;
#pragma unroll
  for (int j = 0; j < 4; ++j) {
    float a0 = fmaxf((v[2 * j] - mean) * rstd * (j < 2 ? s0[2 * j] : s1[2 * j - 4])
                         + (j < 2 ? c0[2 * j] : c1[2 * j - 4]), 0.f);
    float a1 = fmaxf((v[2 * j + 1] - mean) * rstd
                         * (j < 2 ? s0[2 * j + 1] : s1[2 * j - 3])
                         + (j < 2 ? c0[2 * j + 1] : c1[2 * j - 3]), 0.f);
    w[j] = (unsigned int)f2bf(a0) | ((unsigned int)f2bf(a1) << 16);
  }
  *(uint4v*)(Y + (size_t)row * 512 + lane * 8) = w;
}

// ---------------- phase B: GRU scan -----------------------------------------
// 256 blocks (8 row-groups x 32 col-chunks) x 256 threads, 1 block/CU (LDS).
// MFMA swapped (W as A, h as B): each thread owns (1 row, 4 cols) of D ->
// one 8B coherent h store, one dones byte, float4 outh store. gin staged
// from its scan-blocked layout: per chunk = 48KB CONTIGUOUS per block,
// 12 async16/thread every 8 steps, double-buffered; dones staged once.
// Handoff: producer sc0sc1 write-through h + vmcnt(0)-drained barrier +
// sc0sc1 flag publish; consumer sc0sc1 flag poll + plain fresh-region
// h loads (R5 protocol, verified).

__global__ __launch_bounds__(256, 1) void k_gru(
    const unsigned short* __restrict__ Whf, const unsigned short* __restrict__ gin,
    const float* __restrict__ bhn, const int* __restrict__ dI,
    const unsigned char* __restrict__ dB, const unsigned int* __restrict__ flag,
    const unsigned short* __restrict__ hbuf, unsigned short* __restrict__ ybuf,
    float* __restrict__ outh, unsigned int* __restrict__ ready) {
  // LDS: gin [2 bufs][GSTEPS][3 gates][64 rows][16 cols] bf16 = 96KB
  //      dones [128 steps][64 rows] bytes = 8KB       (total 104KB < 160KB)
  __shared__ __align__(16) unsigned short gin_lds[2][GSTEPS * 3 * 64 * 16];
  __shared__ unsigned char d_lds[TT * 64];

  const int tid = threadIdx.x, wave = tid >> 6, lane = tid & 63;
  const int quad = lane >> 4, l15 = lane & 15;
  const int rt = blockIdx.x & 7;    // row group (64 rows)
  const int cc = blockIdx.x >> 3;   // col chunk (16 cols per gate), 0..31
  const int r0b = rt * 64;          // block's first batch row
  const int rowb = wave * 16 + l15; // thread's row within block
  const int row = r0b + rowb;       // global batch row
  const int c0 = cc * 16 + quad * 4;  // thread's first gate-col (per gate)
  const int bytemode = (int)(*flag);
  const float4v bhn4 = *(const float4v*)(bhn + c0);

  // this block's contiguous gin stream: base of [t][g][64][16] blocks
  const unsigned short* gsrc = gin + (size_t)(rt * 32 + cc) * 128 * 3072;

  // chunk staging: GSTEPS*3072 elements contiguous = 3072 16B units,
  // 12 per thread, straight-line copy
  auto stage_gin = [&](int buf, int t0) {
    const unsigned short* src = gsrc + (size_t)t0 * 3072;
#pragma unroll
    for (int r = 0; r < 12; ++r) {
      async16(&gin_lds[buf][(size_t)(r * 256 + wave * 64) * 8],
              src + (size_t)(r * 256 + tid) * 8);
    }
  };

  // prologue: stage chunk 0, stage all dones, load weights + hprev
  stage_gin(0, 0);
#pragma unroll
  for (int r = 0; r < 32; ++r) {
    int idx = r * 256 + tid;         // idx = t*64 + rowInBlock
    int t = idx >> 6, rr = idx & 63;
    int gidx = t * 512 + r0b + rr;
    d_lds[idx] = bytemode ? dB[gidx] : (unsigned char)(dI[gidx] != 0);
  }

  // weight-stationary A fragments: [gate][k-step]
  short8 bw[3][16];
#pragma unroll
  for (int kc = 0; kc < 16; ++kc)
#pragma unroll
    for (int g = 0; g < 3; ++g) {
      size_t u = (size_t)(kc * 4 + quad) * 1536 + (g * 512 + cc * 16 + l15);
      bw[g][kc] = *(const short8*)(Whf + u * 8);
    }

  // own h carried in registers (fp32): 4 consecutive cols of own row
  float hprev[4];
  {
    unsigned long long w = *(const unsigned long long*)(hbuf + (size_t)row * 512 + c0);
#pragma unroll
    for (int i = 0; i < 4; ++i) hprev[i] = bf2f((unsigned short)(w >> (16 * i)));
  }

  __syncthreads();  // drains staging vmcnt + dones ds_writes

  for (int t = 0; t < TT; ++t) {
    if (t > 0) {
      if (wave == 0) {
        // 32 lanes poll 32 per-producer flags (128B apart) in parallel
        const unsigned int* fp =
            ready + (((size_t)rt * 130 + t) * 32 + (lane & 31)) * FSTRIDE;
        unsigned int v;
        int guard = 0;
        do {
          v = load_u32_coh(fp);
        } while (__ballot(v == 0u) != 0ull && ++guard < (1 << 22));
      }
      __syncthreads();
      asm volatile("" ::: "memory");  // no hoisting h loads above the wait
    }

    // B fragments: h rows, plain cached loads from per-step-fresh region
    const unsigned short* hsrc =
        (t == 0) ? hbuf : ybuf + (size_t)(t - 1) * 262144;
    const unsigned short* ap = hsrc + (size_t)row * 512 + quad * 8;
    short8 af[16];
#pragma unroll
    for (int kc = 0; kc < 16; ++kc) af[kc] = *(const short8*)(ap + kc * 32);

    const int dd = (int)d_lds[(t << 6) + rowb];
    if (dd) {
      const short8 z8 = {0, 0, 0, 0, 0, 0, 0, 0};
#pragma unroll
      for (int kc = 0; kc < 16; ++kc) af[kc] = z8;
    }

    // stage next chunk (drained by this step's ending __syncthreads)
    if ((t & (GSTEPS - 1)) == 0 && t + GSTEPS < TT)
      stage_gin(((t >> 3) + 1) & 1, t + GSTEPS);

    // gin from LDS: 3x ds_read_b64 (4 consecutive cols per gate)
    const int sl = t & (GSTEPS - 1), bufc = (t >> 3) & 1;
    float gr[4], gz[4], gn[4];
    {
      const unsigned short* gl =
          &gin_lds[bufc][((size_t)(sl * 3) * 64 + rowb) * 16 + quad * 4];
      unsigned long long w0 = *(const unsigned long long*)(gl);
      unsigned long long w1 = *(const unsigned long long*)(gl + 1024);
      unsigned long long w2 = *(const unsigned long long*)(gl + 2048);
#pragma unroll
      for (int i = 0; i < 4; ++i) {
        gr[i] = bf2f((unsigned short)(w0 >> (16 * i)));
        gz[i] = bf2f((unsigned short)(w1 >> (16 * i)));
        gn[i] = bf2f((unsigned short)(w2 >> (16 * i)));
      }
    }

    float4v a0 = {0.f, 0.f, 0.f, 0.f}, a1 = a0, a2 = a0;
#pragma unroll
    for (int kc = 0; kc < 16; ++kc) {
      a0 = __builtin_amdgcn_mfma_f32_16x16x32_bf16(bw[0][kc], af[kc], a0, 0, 0, 0);
      a1 = __builtin_amdgcn_mfma_f32_16x16x32_bf16(bw[1][kc], af[kc], a1, 0, 0, 0);
      a2 = __builtin_amdgcn_mfma_f32_16x16x32_bf16(bw[2][kc], af[kc], a2, 0, 0, 0);
    }

    unsigned short* ydst = ybuf + (size_t)t * 262144;
    float hv[4];
#pragma unroll
    for (int i = 0; i < 4; ++i) {
      float hold = dd ? 0.f : hprev[i];
      float r = 1.f / (1.f + __expf(-(a0[i] + gr[i])));
      float z = 1.f / (1.f + __expf(-(a1[i] + gz[i])));
      float npre = gn[i] + r * (a2[i] + bhn4[i]);
      float n = 1.f - 2.f / (1.f + __expf(2.f * npre));  // tanh, inf-safe
      hv[i] = (1.f - z) * n + z * hold;
      hprev[i] = hv[i];
    }
    {
      unsigned long long pk = (unsigned long long)f2bf(hv[0])
          | ((unsigned long long)f2bf(hv[1]) << 16)
          | ((unsigned long long)f2bf(hv[2]) << 32)
          | ((unsigned long long)f2bf(hv[3]) << 48);
      // write-through to coherence point (IC): next step's cross-XCD input
      store_u64_coh(ydst + (size_t)row * 512 + c0, pk);
    }
    if (t == TT - 1) {
      float4v o = {hv[0], hv[1], hv[2], hv[3]};
      *(float4v*)(outh + (size_t)row * 512 + c0) = o;
    }

    __syncthreads();  // s_waitcnt vmcnt(0) before s_barrier: h at IC
    if (tid == 0)
      store_u32_coh(&ready[(((size_t)rt * 130 + t + 1) * 32 + cc) * FSTRIDE], 1u);
  }
}

// ---------------- phase C: q = y @ w_out + b_out (N padded to 64) -----------
// BK=64: 8 k-iterations, 2x8 MFMA per iteration.

__global__ __launch_bounds__(256) void k_qout(
    const unsigned short* __restrict__ Yb, const unsigned short* __restrict__ Wt,
    const float* __restrict__ bout, float* __restrict__ Q) {
  __shared__ unsigned short As[8192];
  __shared__ unsigned short Bs[4096];
  const int tid = threadIdx.x, wave = tid >> 6, lane = tid & 63;
  const int quad = lane >> 4, l15 = lane & 15;
  const int m0 = blockIdx.x * 128;

  float4v acc[2][4];
#pragma unroll
  for (int a = 0; a < 2; ++a)
#pragma unroll
    for (int b = 0; b < 4; ++b) acc[a][b] = (float4v){0.f, 0.f, 0.f, 0.f};

  for (int k0 = 0; k0 < 512; k0 += 64) {
#pragma unroll
    for (int r = 0; r < 4; ++r) {
      int u = r * 256 + wave * 64 + lane;
      int ch = u >> 7, mm = u & 127;
      async16(&As[(size_t)(r * 256 + wave * 64) * 8],
              Yb + (size_t)(m0 + mm) * 512 + k0 + ch * 8);
    }
#pragma unroll
    for (int r = 0; r < 2; ++r) {
      int u = r * 256 + wave * 64 + lane;
      int ch = u >> 6, nn = u & 63;
      async16(&Bs[(size_t)(r * 256 + wave * 64) * 8],
              Wt + (size_t)nn * 512 + k0 + ch * 8);
    }
    __syncthreads();
#pragma unroll
    for (int kk = 0; kk < 2; ++kk) {
      short8 afr[2], bfr[4];
#pragma unroll
      for (int mi = 0; mi < 2; ++mi)
        afr[mi] = *(const short8*)
            &As[((kk * 4 + quad) * 128 + wave * 32 + mi * 16 + l15) * 8];
#pragma unroll
      for (int ni = 0; ni < 4; ++ni)
        bfr[ni] = *(const short8*)
            &Bs[((kk * 4 + quad) * 64 + ni * 16 + l15) * 8];
#pragma unroll
      for (int mi = 0; mi < 2; ++mi)
#pragma unroll
        for (int ni = 0; ni < 4; ++ni)
          acc[mi][ni] = __builtin_amdgcn_mfma_f32_16x16x32_bf16(
              afr[mi], bfr[ni], acc[mi][ni], 0, 0, 0);
    }
    __syncthreads();
  }
#pragma unroll
  for (int mi = 0; mi < 2; ++mi)
#pragma unroll
    for (int ni = 0; ni < 4; ++ni)
#pragma unroll
      for (int i = 0; i < 4; ++i) {
        int row = m0 + wave * 32 + mi * 16 + quad * 4 + i;
        int colq = ni * 16 + l15;
        if (colq < AD) Q[(size_t)row * AD + colq] = acc[mi][ni][i] + bout[colq];
      }
}

// ---------------- launch ----------------------------------------------------

extern "C" void kernel_launch(void* const* d_in, const int* in_sizes, int n_in,
                              void* d_out, int out_size, void* d_ws,
                              size_t ws_size, hipStream_t stream) {
  const float* hidden = (const float*)d_in[0];
  const float* obs = (const float*)d_in[1];
  const void* dones = d_in[2];
  const int* acts = (const int*)d_in[3];
  const float* w0 = (const float*)d_in[4];
  const float* b0 = (const float*)d_in[5];
  const float* ln0s = (const float*)d_in[6];
  const float* ln0b = (const float*)d_in[7];
  const float* w1 = (const float*)d_in[8];
  const float* b1 = (const float*)d_in[9];
  const float* ln1s = (const float*)d_in[10];
  const float* ln1b = (const float*)d_in[11];
  const float* wir = (const float*)d_in[12];
  const float* bir = (const float*)d_in[13];
  const float* wiz = (const float*)d_in[14];
  const float* biz = (const float*)d_in[15];
  const float* win = (const float*)d_in[16];
  const float* bin = (const float*)d_in[17];
  const float* whr = (const float*)d_in[18];
  const float* whz = (const float*)d_in[19];
  const float* whn = (const float*)d_in[20];
  const float* bhn = (const float*)d_in[21];
  const float* wout = (const float*)d_in[22];
  const float* bout = (const float*)d_in[23];

  char* ws = (char*)d_ws;
  unsigned short* bufA = (unsigned short*)(ws);                   // 64MB: obs_bf -> x1 -> x2 -> [ready]
  unsigned short* bufB = (unsigned short*)(ws + 67108864ULL);     // 64MB: pre0 -> pre1 -> y/h
  unsigned short* gin = (unsigned short*)(ws + 134217728ULL);     // 192MB (scan-blocked)
  char* D = ws + 134217728ULL + 201326592ULL;
  unsigned short* W0at = (unsigned short*)(D);                    // 512KB
  unsigned short* W1t = (unsigned short*)(D + 524288);            // 512KB
  unsigned short* Wit = (unsigned short*)(D + 1048576);           // 1.5MB
  unsigned short* Whf = (unsigned short*)(D + 2621440);           // 1.5MB
  unsigned short* WoutT = (unsigned short*)(D + 4194304);         // 64KB
  unsigned short* w0act = (unsigned short*)(D + 4259840);         // 32KB
  float* gib = (float*)(D + 4292608);                             // 8KB
  unsigned short* hbuf = (unsigned short*)(D + 4300800);          // 512KB init h
  unsigned int* flag = (unsigned int*)(D + 4825088);              // 4B dones-dtype
  unsigned int* ready = (unsigned int*)ws;                        // 4.26MB in bufA

  (void)in_sizes; (void)n_in; (void)out_size; (void)ws_size;

  k_conv_obs<<<32768, 256, 0, stream>>>(obs, bufA, flag);
  k_prep_t<<<dim3(1024, 5), 256, 0, stream>>>(w0, w1, wir, wiz, win, W0at, W1t, Wit);
  k_prep_whf<<<3072, 256, 0, stream>>>(whr, whz, whn, Whf);
  k_prep_misc<<<1024, 256, 0, stream>>>(w0, bir, biz, bin, wout, hidden,
                                        (const int*)dones, w0act, gib, WoutT,
                                        hbuf, flag);
  // encoder
  k_gemm_bt<1><<<dim3(512, 4), 256, 0, stream>>>(bufA, W0at, bufB, 512, b0, w0act, acts);
  k_ln_relu<<<16384, 256, 0, stream>>>(bufB, bufA, ln0s, ln0b);
  k_gemm_bt<0><<<dim3(512, 4), 256, 0, stream>>>(bufA, W1t, bufB, 512, b1, nullptr, nullptr);
  k_ln_relu<<<16384, 256, 0, stream>>>(bufB, bufA, ln1s, ln1b);
  // GRU input projections (biases fused), written scan-blocked
  k_gemm_bt<2><<<dim3(512, 12), 256, 0, stream>>>(bufA, Wit, gin, 1536, gib, nullptr, nullptr);
  // bufA is now dead: zero the spread flag array there
  k_zero<<<1041, 256, 0, stream>>>(ready);
  // sequential scan; writes new_hidden to d_out[0:262144] and y/h to bufB
  k_gru<<<256, 256, 0, stream>>>(Whf, gin, bhn, (const int*)dones,
                                 (const unsigned char*)dones, flag, hbuf, bufB,
                                 (float*)d_out, ready);
  // output head -> d_out[262144:]
  k_qout<<<512, 256, 0, stream>>>(bufB, WoutT, bout, (float*)d_out + 262144);
}

// Round 7
// 1230.351 us; speedup vs baseline: 1.0199x; 1.0199x over previous
//
#include <hip/hip_runtime.h>
#include <cstdint>
#include <cstddef>

// RNNQNetwork: fused MLP encoder (row-complete MFMA GEMM + in-epilogue
// LayerNorm+ReLU) -> 128-step GRU scan (weight-stationary distributed GEMM,
// sc0sc1 cross-block handoff) -> output head GEMM.
//
// R11 = R10 resubmitted (container failed twice = infra, same signature as
// R7 which passed unchanged as R8; bounds/LDS/VGPR/sync audit found no
// GPU-fault surface in k_enc). R10's change: replace 128x128-tile GEMMs +
// separate LN kernels with k_enc: 512-thread blocks computing 128 rows x
// FULL 512 cols (A staged once/block, B panel once/block), LN+ReLU fused
// in the epilogue via shfl_xor row reduction (LN on fp32 accs - more
// accurate than old bf16 round-trip). gin = k_enc<2> grid (512,3), one
// gate per blockIdx.y, same scan-blocked epilogue k_gru already reads.
// k_gru/k_qout/prep untouched (verified 517us path).

#define TT 128
#define BBATCH 512
#define HH 512
#define MM 65536   // T*B
#define AD 18
#define GSTEPS 8   // gin staging chunk (steps per LDS buffer)
#define FSTRIDE 32 // u32s between flags (128B: one line per flag)
#define READY_U32 1064960  // ((8*130)*32) flags * FSTRIDE

typedef __attribute__((ext_vector_type(8))) short short8;
typedef __attribute__((ext_vector_type(4))) float float4v;
typedef __attribute__((ext_vector_type(4))) unsigned int uint4v;

__device__ __forceinline__ unsigned short f2bf(float f) {
  union { float f; unsigned int u; } v; v.f = f;
  unsigned int r = v.u + 0x7fffu + ((v.u >> 16) & 1u);  // RNE
  return (unsigned short)(r >> 16);
}
__device__ __forceinline__ float bf2f(unsigned short h) {
  union { unsigned int u; float f; } v; v.u = ((unsigned int)h) << 16;
  return v.f;
}

// per-access coherent (coherence-point) ops: sc0 sc1 = device-scope, no fence
__device__ __forceinline__ unsigned int load_u32_coh(const unsigned int* p) {
  unsigned int v;
  asm volatile("global_load_dword %0, %1, off sc0 sc1\n\ts_waitcnt vmcnt(0)"
               : "=v"(v) : "v"(p) : "memory");
  return v;
}
__device__ __forceinline__ void store_u32_coh(unsigned int* p, unsigned int v) {
  asm volatile("global_store_dword %0, %1, off sc0 sc1"
               :: "v"(p), "v"(v) : "memory");
}
__device__ __forceinline__ void store_u64_coh(void* p, unsigned long long v) {
  asm volatile("global_store_dwordx2 %0, %1, off sc0 sc1"
               :: "v"(p), "v"(v) : "memory");
}

// async global->LDS, 16B per lane. LDS dest must be wave-uniform base;
// lanes deposit at base + lane*16 (guide section 5 caveat).
typedef __attribute__((address_space(3))) unsigned int* lds_u32p;
typedef const __attribute__((address_space(1))) unsigned int* glb_u32p;
__device__ __forceinline__ void async16(void* lds, const void* g) {
  __builtin_amdgcn_global_load_lds(
      (glb_u32p)(unsigned long long)g,
      (lds_u32p)(unsigned int)(unsigned long long)lds, 16, 0, 0);
}

// ---------------- prep kernels ----------------

// obs fp32 -> bf16 (packed 4/thread); also zero the dones-format flag.
__global__ __launch_bounds__(256) void k_conv_obs(
    const float* __restrict__ src, unsigned short* __restrict__ dst,
    unsigned int* __restrict__ flag) {
  if (blockIdx.x == 0 && threadIdx.x == 0) *flag = 0u;
  int i = blockIdx.x * 256 + threadIdx.x;      // grid sized exactly
  float4v v = ((const float4v*)src)[i];
  unsigned long long pk = (unsigned long long)f2bf(v[0])
      | ((unsigned long long)f2bf(v[1]) << 16)
      | ((unsigned long long)f2bf(v[2]) << 32)
      | ((unsigned long long)f2bf(v[3]) << 48);
  ((unsigned long long*)dst)[i] = pk;
}

// Transpose [512][512] fp32 weights -> [N][K] bf16 (B^T layout).
__global__ __launch_bounds__(256) void k_prep_t(
    const float* __restrict__ w0, const float* __restrict__ w1,
    const float* __restrict__ wir, const float* __restrict__ wiz,
    const float* __restrict__ win,
    unsigned short* __restrict__ W0at, unsigned short* __restrict__ W1t,
    unsigned short* __restrict__ Wit) {
  int o = blockIdx.x * 256 + threadIdx.x;  // o = n*512 + k
  int n = o >> 9, k = o & 511;
  int z = blockIdx.y;
  const float* s = (z == 0) ? w0 : (z == 1) ? w1 : (z == 2) ? wir
                 : (z == 3) ? wiz : win;
  unsigned short b = f2bf(s[k * 512 + n]);
  if (z == 0) W0at[o] = b;
  else if (z == 1) W1t[o] = b;
  else Wit[(size_t)(z - 2) * 262144 + o] = b;
}

// Hidden weights [w_hr|w_hz|w_hn] -> MFMA-fragment layout:
// Whf unit (k>>3)*1536 + n holds bf16 W[k0..k0+8][n] contiguously (16B).
__global__ __launch_bounds__(256) void k_prep_whf(
    const float* __restrict__ whr, const float* __restrict__ whz,
    const float* __restrict__ whn, unsigned short* __restrict__ Whf) {
  int i = blockIdx.x * 256 + threadIdx.x;  // < 512*1536, grid exact
  int k = i / 1536, n = i - k * 1536;
  const float* s = (n < 512) ? whr : (n < 1024) ? whz : whn;
  float v = s[k * 512 + (n & 511)];
  Whf[((size_t)(k >> 3) * 1536 + n) * 8 + (k & 7)] = f2bf(v);
}

// Misc: w0 action rows (bf16), combined gru-input bias, w_out^T padded to 64,
// initial h (bf16), detect dones dtype.
__global__ __launch_bounds__(256) void k_prep_misc(
    const float* __restrict__ w0, const float* __restrict__ bir,
    const float* __restrict__ biz, const float* __restrict__ bin,
    const float* __restrict__ wout, const float* __restrict__ hidden,
    const int* __restrict__ dI,
    unsigned short* __restrict__ w0act, float* __restrict__ gib,
    unsigned short* __restrict__ WoutT, unsigned short* __restrict__ hbuf,
    unsigned int* __restrict__ flag) {
  int i = blockIdx.x * 256 + threadIdx.x;  // grid 1024 -> i < 262144
  if (i < 9216) {
    int a = i >> 9, n = i & 511;
    w0act[i] = f2bf(w0[(512 + a) * 512 + n]);
  }
  if (i < 1536)
    gib[i] = (i < 512) ? bir[i] : (i < 1024) ? biz[i - 512] : bin[i - 1024];
  if (i < 32768) {
    int n = i >> 9, k = i & 511;
    WoutT[i] = f2bf(n < AD ? wout[k * AD + n] : 0.f);
  }
  if (i < 262144) hbuf[i] = f2bf(hidden[i]);
  // dones dtype probe: first 64KB viewed as int32. int32 bools are only
  // {0,1}; packed byte-bools produce values with bits above bit0.
  if (i < 16384) { if (dI[i] & 0xFFFFFFFE) atomicOr(flag, 1u); }
}

// zero the spread flag array (lives in bufA, dead after the gin GEMM)
__global__ __launch_bounds__(256) void k_zero(unsigned int* __restrict__ p) {
  int i = (blockIdx.x * 256 + threadIdx.x) * 4;
  if (i < READY_U32) *(uint4v*)(p + i) = (uint4v){0u, 0u, 0u, 0u};
}

// ---------------- fused encoder GEMM: 128 rows x full 512 cols per block ----
// 512 threads = 8 waves (2M x 4N); per wave 64 rows x 128 cols = 4x8 MFMA
// tiles; acc 128 VGPR. A staged once/block (16KB/iter), B panel (64KB/iter),
// single-buffered, BK=64, 8 k-iterations.
// MODE 0: layer0  (+bias +w0act[act] gather, LN+ReLU, write bf16)
// MODE 1: layer1  (+bias, LN+ReLU, write bf16)
// MODE 2: gin gate g=blockIdx.y (+gib bias, scan-blocked write for k_gru)

template <int MODE>
__global__ __launch_bounds__(512, 1) void k_enc(
    const unsigned short* __restrict__ Ab,   // [M][512] bf16
    const unsigned short* __restrict__ Btb,  // [N][512] bf16 (MODE2: slabs)
    unsigned short* __restrict__ Cb,
    const float* __restrict__ bias,          // (MODE2: gib[1536])
    const float* __restrict__ lnS, const float* __restrict__ lnB,
    const unsigned short* __restrict__ gW,   // [18][512] bf16 (MODE0)
    const int* __restrict__ acts) {
  __shared__ unsigned short As[8192];    // [8 ch][128 m][8]  16KB
  __shared__ unsigned short Bs[32768];   // [8 ch][512 n][8]  64KB
  __shared__ float part[128][4][2];      // row partials per N-wave (4KB)
  __shared__ float stats[128][2];        // mean, rstd (1KB)

  const int tid = threadIdx.x, wave = tid >> 6, lane = tid & 63;
  const int quad = lane >> 4, l15 = lane & 15;
  const int wm = wave >> 2, wn = wave & 3;
  const int m0 = blockIdx.x * 128;
  const int g = (MODE == 2) ? blockIdx.y : 0;
  const unsigned short* Bt = Btb + (size_t)g * 262144;
  const float* bi = bias + g * 512;

  float4v acc[4][8];
#pragma unroll
  for (int a = 0; a < 4; ++a)
#pragma unroll
    for (int b = 0; b < 8; ++b) acc[a][b] = (float4v){0.f, 0.f, 0.f, 0.f};

  for (int k0 = 0; k0 < 512; k0 += 64) {
#pragma unroll
    for (int r = 0; r < 2; ++r) {      // A: 1024 units, 2/thread
      int u = r * 512 + tid;
      int ch = u >> 7, mm = u & 127;
      async16(&As[(size_t)(r * 512 + wave * 64) * 8],
              Ab + (size_t)(m0 + mm) * 512 + k0 + ch * 8);
    }
#pragma unroll
    for (int r = 0; r < 8; ++r) {      // B: 4096 units, 8/thread
      int u = r * 512 + tid;
      int ch = u >> 9, nn = u & 511;
      async16(&Bs[(size_t)(r * 512 + wave * 64) * 8],
              Bt + (size_t)nn * 512 + k0 + ch * 8);
    }
    __syncthreads();  // compiler drains vmcnt before s_barrier
#pragma unroll
    for (int kk = 0; kk < 2; ++kk) {
      short8 afr[4], bfr[8];
#pragma unroll
      for (int mi = 0; mi < 4; ++mi)
        afr[mi] = *(const short8*)
            &As[((kk * 4 + quad) * 128 + wm * 64 + mi * 16 + l15) * 8];
#pragma unroll
      for (int ni = 0; ni < 8; ++ni)
        bfr[ni] = *(const short8*)
            &Bs[((kk * 4 + quad) * 512 + wn * 128 + ni * 16 + l15) * 8];
#pragma unroll
      for (int mi = 0; mi < 4; ++mi)
#pragma unroll
        for (int ni = 0; ni < 8; ++ni)
          acc[mi][ni] = __builtin_amdgcn_mfma_f32_16x16x32_bf16(
              afr[mi], bfr[ni], acc[mi][ni], 0, 0, 0);
    }
    __syncthreads();
  }

  // bias (+one-hot gather) in fp32, into acc
  float bcol[8];
#pragma unroll
  for (int ni = 0; ni < 8; ++ni) bcol[ni] = bi[wn * 128 + ni * 16 + l15];
#pragma unroll
  for (int mi = 0; mi < 4; ++mi)
#pragma unroll
    for (int i = 0; i < 4; ++i) {
      int row = m0 + wm * 64 + mi * 16 + quad * 4 + i;
      int arow = (MODE == 0) ? acts[row] : 0;
#pragma unroll
      for (int ni = 0; ni < 8; ++ni) {
        float v = acc[mi][ni][i] + bcol[ni];
        if (MODE == 0) v += bf2f(gW[arow * 512 + wn * 128 + ni * 16 + l15]);
        acc[mi][ni][i] = v;
      }
    }

  if (MODE <= 1) {
    // ---- fused LayerNorm + ReLU ----
    // per-(row) partial over this thread's 8 cols, reduce over l15 via
    // shfl_xor (same-row lanes), then cross-N-wave via tiny LDS.
#pragma unroll
    for (int mi = 0; mi < 4; ++mi)
#pragma unroll
      for (int i = 0; i < 4; ++i) {
        float s = 0.f, q = 0.f;
#pragma unroll
        for (int ni = 0; ni < 8; ++ni) {
          float v = acc[mi][ni][i];
          s += v; q += v * v;
        }
#pragma unroll
        for (int d = 1; d < 16; d <<= 1) {
          s += __shfl_xor(s, d, 64);
          q += __shfl_xor(q, d, 64);
        }
        if (l15 == 0) {
          int rowl = wm * 64 + mi * 16 + quad * 4 + i;
          part[rowl][wn][0] = s;
          part[rowl][wn][1] = q;
        }
      }
    __syncthreads();
    if (tid < 128) {
      float s = part[tid][0][0] + part[tid][1][0] + part[tid][2][0] + part[tid][3][0];
      float q = part[tid][0][1] + part[tid][1][1] + part[tid][2][1] + part[tid][3][1];
      float mean = s * (1.f / 512.f);
      float var = fmaxf(q * (1.f / 512.f) - mean * mean, 0.f);
      stats[tid][0] = mean;
      stats[tid][1] = rsqrtf(var + 1e-6f);
    }
    __syncthreads();
    float sc8[8], cb8[8];
#pragma unroll
    for (int ni = 0; ni < 8; ++ni) {
      int col = wn * 128 + ni * 16 + l15;
      sc8[ni] = lnS[col];
      cb8[ni] = lnB[col];
    }
#pragma unroll
    for (int mi = 0; mi < 4; ++mi)
#pragma unroll
      for (int i = 0; i < 4; ++i) {
        int rowl = wm * 64 + mi * 16 + quad * 4 + i;
        float mean = stats[rowl][0], rstd = stats[rowl][1];
        int row = m0 + rowl;
#pragma unroll
        for (int ni = 0; ni < 8; ++ni) {
          int col = wn * 128 + ni * 16 + l15;
          float v = fmaxf((acc[mi][ni][i] - mean) * rstd * sc8[ni] + cb8[ni], 0.f);
          Cb[(size_t)row * 512 + col] = f2bf(v);
        }
      }
  } else {
    // ---- MODE 2: scan-blocked write for k_gru ----
#pragma unroll
    for (int mi = 0; mi < 4; ++mi)
#pragma unroll
      for (int i = 0; i < 4; ++i) {
        int row = m0 + wm * 64 + mi * 16 + quad * 4 + i;
        int t = row >> 9, b = row & 511;
#pragma unroll
        for (int ni = 0; ni < 8; ++ni) {
          int c = wn * 128 + ni * 16 + l15;
          size_t dst = ((size_t)((b >> 6) * 32 + (c >> 4)) * 128 + t) * 3072
                     + (size_t)g * 1024 + (b & 63) * 16 + (c & 15);
          Cb[dst] = f2bf(acc[mi][ni][i]);
        }
      }
  }
}

// ---------------- phase B: GRU scan (untouched, verified 517us) -------------
// 256 blocks (8 row-groups x 32 col-chunks) x 256 threads, 1 block/CU (LDS).
// MFMA swapped (W as A, h as B): each thread owns (1 row, 4 cols) of D ->
// one 8B coherent h store, one dones byte, float4 outh store. gin staged
// from its scan-blocked layout: per chunk = 48KB CONTIGUOUS per block,
// 12 async16/thread every 8 steps, double-buffered; dones staged once.
// Handoff: producer sc0sc1 write-through h + vmcnt(0)-drained barrier +
// sc0sc1 flag publish; consumer sc0sc1 flag poll + plain fresh-region
// h loads (R5 protocol, verified).

__global__ __launch_bounds__(256, 1) void k_gru(
    const unsigned short* __restrict__ Whf, const unsigned short* __restrict__ gin,
    const float* __restrict__ bhn, const int* __restrict__ dI,
    const unsigned char* __restrict__ dB, const unsigned int* __restrict__ flag,
    const unsigned short* __restrict__ hbuf, unsigned short* __restrict__ ybuf,
    float* __restrict__ outh, unsigned int* __restrict__ ready) {
  // LDS: gin [2 bufs][GSTEPS][3 gates][64 rows][16 cols] bf16 = 96KB
  //      dones [128 steps][64 rows] bytes = 8KB       (total 104KB < 160KB)
  __shared__ __align__(16) unsigned short gin_lds[2][GSTEPS * 3 * 64 * 16];
  __shared__ unsigned char d_lds[TT * 64];

  const int tid = threadIdx.x, wave = tid >> 6, lane = tid & 63;
  const int quad = lane >> 4, l15 = lane & 15;
  const int rt = blockIdx.x & 7;    // row group (64 rows)
  const int cc = blockIdx.x >> 3;   // col chunk (16 cols per gate), 0..31
  const int r0b = rt * 64;          // block's first batch row
  const int rowb = wave * 16 + l15; // thread's row within block
  const int row = r0b + rowb;       // global batch row
  const int c0 = cc * 16 + quad * 4;  // thread's first gate-col (per gate)
  const int bytemode = (int)(*flag);
  const float4v bhn4 = *(const float4v*)(bhn + c0);

  // this block's contiguous gin stream: base of [t][g][64][16] blocks
  const unsigned short* gsrc = gin + (size_t)(rt * 32 + cc) * 128 * 3072;

  // chunk staging: GSTEPS*3072 elements contiguous = 3072 16B units,
  // 12 per thread, straight-line copy
  auto stage_gin = [&](int buf, int t0) {
    const unsigned short* src = gsrc + (size_t)t0 * 3072;
#pragma unroll
    for (int r = 0; r < 12; ++r) {
      async16(&gin_lds[buf][(size_t)(r * 256 + wave * 64) * 8],
              src + (size_t)(r * 256 + tid) * 8);
    }
  };

  // prologue: stage chunk 0, stage all dones, load weights + hprev
  stage_gin(0, 0);
#pragma unroll
  for (int r = 0; r < 32; ++r) {
    int idx = r * 256 + tid;         // idx = t*64 + rowInBlock
    int t = idx >> 6, rr = idx & 63;
    int gidx = t * 512 + r0b + rr;
    d_lds[idx] = bytemode ? dB[gidx] : (unsigned char)(dI[gidx] != 0);
  }

  // weight-stationary A fragments: [gate][k-step]
  short8 bw[3][16];
#pragma unroll
  for (int kc = 0; kc < 16; ++kc)
#pragma unroll
    for (int g = 0; g < 3; ++g) {
      size_t u = (size_t)(kc * 4 + quad) * 1536 + (g * 512 + cc * 16 + l15);
      bw[g][kc] = *(const short8*)(Whf + u * 8);
    }

  // own h carried in registers (fp32): 4 consecutive cols of own row
  float hprev[4];
  {
    unsigned long long w = *(const unsigned long long*)(hbuf + (size_t)row * 512 + c0);
#pragma unroll
    for (int i = 0; i < 4; ++i) hprev[i] = bf2f((unsigned short)(w >> (16 * i)));
  }

  __syncthreads();  // drains staging vmcnt + dones ds_writes

  for (int t = 0; t < TT; ++t) {
    if (t > 0) {
      if (wave == 0) {
        // 32 lanes poll 32 per-producer flags (128B apart) in parallel
        const unsigned int* fp =
            ready + (((size_t)rt * 130 + t) * 32 + (lane & 31)) * FSTRIDE;
        unsigned int v;
        int guard = 0;
        do {
          v = load_u32_coh(fp);
        } while (__ballot(v == 0u) != 0ull && ++guard < (1 << 22));
      }
      __syncthreads();
      asm volatile("" ::: "memory");  // no hoisting h loads above the wait
    }

    // B fragments: h rows, plain cached loads from per-step-fresh region
    const unsigned short* hsrc =
        (t == 0) ? hbuf : ybuf + (size_t)(t - 1) * 262144;
    const unsigned short* ap = hsrc + (size_t)row * 512 + quad * 8;
    short8 af[16];
#pragma unroll
    for (int kc = 0; kc < 16; ++kc) af[kc] = *(const short8*)(ap + kc * 32);

    const int dd = (int)d_lds[(t << 6) + rowb];
    if (dd) {
      const short8 z8 = {0, 0, 0, 0, 0, 0, 0, 0};
#pragma unroll
      for (int kc = 0; kc < 16; ++kc) af[kc] = z8;
    }

    // stage next chunk (drained by this step's ending __syncthreads)
    if ((t & (GSTEPS - 1)) == 0 && t + GSTEPS < TT)
      stage_gin(((t >> 3) + 1) & 1, t + GSTEPS);

    // gin from LDS: 3x ds_read_b64 (4 consecutive cols per gate)
    const int sl = t & (GSTEPS - 1), bufc = (t >> 3) & 1;
    float gr[4], gz[4], gn[4];
    {
      const unsigned short* gl =
          &gin_lds[bufc][((size_t)(sl * 3) * 64 + rowb) * 16 + quad * 4];
      unsigned long long w0 = *(const unsigned long long*)(gl);
      unsigned long long w1 = *(const unsigned long long*)(gl + 1024);
      unsigned long long w2 = *(const unsigned long long*)(gl + 2048);
#pragma unroll
      for (int i = 0; i < 4; ++i) {
        gr[i] = bf2f((unsigned short)(w0 >> (16 * i)));
        gz[i] = bf2f((unsigned short)(w1 >> (16 * i)));
        gn[i] = bf2f((unsigned short)(w2 >> (16 * i)));
      }
    }

    float4v a0 = {0.f, 0.f, 0.f, 0.f}, a1 = a0, a2 = a0;
#pragma unroll
    for (int kc = 0; kc < 16; ++kc) {
      a0 = __builtin_amdgcn_mfma_f32_16x16x32_bf16(bw[0][kc], af[kc], a0, 0, 0, 0);
      a1 = __builtin_amdgcn_mfma_f32_16x16x32_bf16(bw[1][kc], af[kc], a1, 0, 0, 0);
      a2 = __builtin_amdgcn_mfma_f32_16x16x32_bf16(bw[2][kc], af[kc], a2, 0, 0, 0);
    }

    unsigned short* ydst = ybuf + (size_t)t * 262144;
    float hv[4];
#pragma unroll
    for (int i = 0; i < 4; ++i) {
      float hold = dd ? 0.f : hprev[i];
      float r = 1.f / (1.f + __expf(-(a0[i] + gr[i])));
      float z = 1.f / (1.f + __expf(-(a1[i] + gz[i])));
      float npre = gn[i] + r * (a2[i] + bhn4[i]);
      float n = 1.f - 2.f / (1.f + __expf(2.f * npre));  // tanh, inf-safe
      hv[i] = (1.f - z) * n + z * hold;
      hprev[i] = hv[i];
    }
    {
      unsigned long long pk = (unsigned long long)f2bf(hv[0])
          | ((unsigned long long)f2bf(hv[1]) << 16)
          | ((unsigned long long)f2bf(hv[2]) << 32)
          | ((unsigned long long)f2bf(hv[3]) << 48);
      // write-through to coherence point (IC): next step's cross-XCD input
      store_u64_coh(ydst + (size_t)row * 512 + c0, pk);
    }
    if (t == TT - 1) {
      float4v o = {hv[0], hv[1], hv[2], hv[3]};
      *(float4v*)(outh + (size_t)row * 512 + c0) = o;
    }

    __syncthreads();  // s_waitcnt vmcnt(0) before s_barrier: h at IC
    if (tid == 0)
      store_u32_coh(&ready[(((size_t)rt * 130 + t + 1) * 32 + cc) * FSTRIDE], 1u);
  }
}

// ---------------- phase C: q = y @ w_out + b_out (N padded to 64) -----------
// BK=64: 8 k-iterations, 2x8 MFMA per iteration.

__global__ __launch_bounds__(256) void k_qout(
    const unsigned short* __restrict__ Yb, const unsigned short* __restrict__ Wt,
    const float* __restrict__ bout, float* __restrict__ Q) {
  __shared__ unsigned short As[8192];
  __shared__ unsigned short Bs[4096];
  const int tid = threadIdx.x, wave = tid >> 6, lane = tid & 63;
  const int quad = lane >> 4, l15 = lane & 15;
  const int m0 = blockIdx.x * 128;

  float4v acc[2][4];
#pragma unroll
  for (int a = 0; a < 2; ++a)
#pragma unroll
    for (int b = 0; b < 4; ++b) acc[a][b] = (float4v){0.f, 0.f, 0.f, 0.f};

  for (int k0 = 0; k0 < 512; k0 += 64) {
#pragma unroll
    for (int r = 0; r < 4; ++r) {
      int u = r * 256 + wave * 64 + lane;
      int ch = u >> 7, mm = u & 127;
      async16(&As[(size_t)(r * 256 + wave * 64) * 8],
              Yb + (size_t)(m0 + mm) * 512 + k0 + ch * 8);
    }
#pragma unroll
    for (int r = 0; r < 2; ++r) {
      int u = r * 256 + wave * 64 + lane;
      int ch = u >> 6, nn = u & 63;
      async16(&Bs[(size_t)(r * 256 + wave * 64) * 8],
              Wt + (size_t)nn * 512 + k0 + ch * 8);
    }
    __syncthreads();
#pragma unroll
    for (int kk = 0; kk < 2; ++kk) {
      short8 afr[2], bfr[4];
#pragma unroll
      for (int mi = 0; mi < 2; ++mi)
        afr[mi] = *(const short8*)
            &As[((kk * 4 + quad) * 128 + wave * 32 + mi * 16 + l15) * 8];
#pragma unroll
      for (int ni = 0; ni < 4; ++ni)
        bfr[ni] = *(const short8*)
            &Bs[((kk * 4 + quad) * 64 + ni * 16 + l15) * 8];
#pragma unroll
      for (int mi = 0; mi < 2; ++mi)
#pragma unroll
        for (int ni = 0; ni < 4; ++ni)
          acc[mi][ni] = __builtin_amdgcn_mfma_f32_16x16x32_bf16(
              afr[mi], bfr[ni], acc[mi][ni], 0, 0, 0);
    }
    __syncthreads();
  }
#pragma unroll
  for (int mi = 0; mi < 2; ++mi)
#pragma unroll
    for (int ni = 0; ni < 4; ++ni)
#pragma unroll
      for (int i = 0; i < 4; ++i) {
        int row = m0 + wave * 32 + mi * 16 + quad * 4 + i;
        int colq = ni * 16 + l15;
        if (colq < AD) Q[(size_t)row * AD + colq] = acc[mi][ni][i] + bout[colq];
      }
}

// ---------------- launch ----------------------------------------------------

extern "C" void kernel_launch(void* const* d_in, const int* in_sizes, int n_in,
                              void* d_out, int out_size, void* d_ws,
                              size_t ws_size, hipStream_t stream) {
  const float* hidden = (const float*)d_in[0];
  const float* obs = (const float*)d_in[1];
  const void* dones = d_in[2];
  const int* acts = (const int*)d_in[3];
  const float* w0 = (const float*)d_in[4];
  const float* b0 = (const float*)d_in[5];
  const float* ln0s = (const float*)d_in[6];
  const float* ln0b = (const float*)d_in[7];
  const float* w1 = (const float*)d_in[8];
  const float* b1 = (const float*)d_in[9];
  const float* ln1s = (const float*)d_in[10];
  const float* ln1b = (const float*)d_in[11];
  const float* wir = (const float*)d_in[12];
  const float* bir = (const float*)d_in[13];
  const float* wiz = (const float*)d_in[14];
  const float* biz = (const float*)d_in[15];
  const float* win = (const float*)d_in[16];
  const float* bin = (const float*)d_in[17];
  const float* whr = (const float*)d_in[18];
  const float* whz = (const float*)d_in[19];
  const float* whn = (const float*)d_in[20];
  const float* bhn = (const float*)d_in[21];
  const float* wout = (const float*)d_in[22];
  const float* bout = (const float*)d_in[23];

  char* ws = (char*)d_ws;
  unsigned short* bufA = (unsigned short*)(ws);                   // 64MB: obs_bf -> x2 -> [ready]
  unsigned short* bufB = (unsigned short*)(ws + 67108864ULL);     // 64MB: x1 -> y/h
  unsigned short* gin = (unsigned short*)(ws + 134217728ULL);     // 192MB (scan-blocked)
  char* D = ws + 134217728ULL + 201326592ULL;
  unsigned short* W0at = (unsigned short*)(D);                    // 512KB
  unsigned short* W1t = (unsigned short*)(D + 524288);            // 512KB
  unsigned short* Wit = (unsigned short*)(D + 1048576);           // 1.5MB
  unsigned short* Whf = (unsigned short*)(D + 2621440);           // 1.5MB
  unsigned short* WoutT = (unsigned short*)(D + 4194304);         // 64KB
  unsigned short* w0act = (unsigned short*)(D + 4259840);         // 32KB
  float* gib = (float*)(D + 4292608);                             // 8KB
  unsigned short* hbuf = (unsigned short*)(D + 4300800);          // 512KB init h
  unsigned int* flag = (unsigned int*)(D + 4825088);              // 4B dones-dtype
  unsigned int* ready = (unsigned int*)ws;                        // 4.26MB in bufA

  (void)in_sizes; (void)n_in; (void)out_size; (void)ws_size;

  k_conv_obs<<<32768, 256, 0, stream>>>(obs, bufA, flag);
  k_prep_t<<<dim3(1024, 5), 256, 0, stream>>>(w0, w1, wir, wiz, win, W0at, W1t, Wit);
  k_prep_whf<<<3072, 256, 0, stream>>>(whr, whz, whn, Whf);
  k_prep_misc<<<1024, 256, 0, stream>>>(w0, bir, biz, bin, wout, hidden,
                                        (const int*)dones, w0act, gib, WoutT,
                                        hbuf, flag);
  // fused encoder: GEMM+bias(+gather)+LN+ReLU per layer
  k_enc<0><<<512, 512, 0, stream>>>(bufA, W0at, bufB, b0, ln0s, ln0b, w0act, acts);
  k_enc<1><<<512, 512, 0, stream>>>(bufB, W1t, bufA, b1, ln1s, ln1b, nullptr, nullptr);
  // GRU input projections (biases fused), written scan-blocked; 1 gate per y
  k_enc<2><<<dim3(512, 3), 512, 0, stream>>>(bufA, Wit, gin, gib, nullptr, nullptr,
                                             nullptr, nullptr);
  // bufA is now dead: zero the spread flag array there
  k_zero<<<1041, 256, 0, stream>>>(ready);
  // sequential scan; writes new_hidden to d_out[0:262144] and y/h to bufB
  k_gru<<<256, 256, 0, stream>>>(Whf, gin, bhn, (const int*)dones,
                                 (const unsigned char*)dones, flag, hbuf, bufB,
                                 (float*)d_out, ready);
  // output head -> d_out[262144:]
  k_qout<<<512, 256, 0, stream>>>(bufB, WoutT, bout, (float*)d_out + 262144);
}

// Round 8
// 1220.981 us; speedup vs baseline: 1.0278x; 1.0077x over previous
//
#include <hip/hip_runtime.h>
#include <cstdint>
#include <cstddef>

// RNNQNetwork: fused MLP encoder (row-complete MFMA GEMM + in-epilogue
// LayerNorm+ReLU, obs fp32 consumed directly) -> 128-step GRU scan
// (weight-stationary distributed GEMM, sc0sc1 handoff) -> output head GEMM.
//
// R12: R11's k_enc fusion saved only ~27us of the ~711us non-gru time ->
// non-gru is NOT GEMM-execution-bound; arithmetic says kernels sum to
// ~630us incl k_gru's 519 => ~500us is launch/harness fixed cost. This
// round minimizes launches (10 -> 7): k_conv_obs deleted (k_enc<0> stages
// obs fp32 directly, converts to bf16 at fragment-load = identical RNE
// numerics, kills a 33K-block kernel + 201MB traffic); 3 prep kernels
// fused into one k_prep (dones-dtype probe now self-contained in one
// block - scans 64KB itself, plain store, no pre-zeroed flag needed).
// k_gru / k_enc<1,2> / k_qout / k_zero byte-identical to verified R11.

#define TT 128
#define BBATCH 512
#define HH 512
#define MM 65536   // T*B
#define AD 18
#define GSTEPS 8   // gin staging chunk (steps per LDS buffer)
#define FSTRIDE 32 // u32s between flags (128B: one line per flag)
#define READY_U32 1064960  // ((8*130)*32) flags * FSTRIDE

typedef __attribute__((ext_vector_type(8))) short short8;
typedef __attribute__((ext_vector_type(4))) float float4v;
typedef __attribute__((ext_vector_type(4))) unsigned int uint4v;

__device__ __forceinline__ unsigned short f2bf(float f) {
  union { float f; unsigned int u; } v; v.f = f;
  unsigned int r = v.u + 0x7fffu + ((v.u >> 16) & 1u);  // RNE
  return (unsigned short)(r >> 16);
}
__device__ __forceinline__ float bf2f(unsigned short h) {
  union { unsigned int u; float f; } v; v.u = ((unsigned int)h) << 16;
  return v.f;
}

// per-access coherent (coherence-point) ops: sc0 sc1 = device-scope, no fence
__device__ __forceinline__ unsigned int load_u32_coh(const unsigned int* p) {
  unsigned int v;
  asm volatile("global_load_dword %0, %1, off sc0 sc1\n\ts_waitcnt vmcnt(0)"
               : "=v"(v) : "v"(p) : "memory");
  return v;
}
__device__ __forceinline__ void store_u32_coh(unsigned int* p, unsigned int v) {
  asm volatile("global_store_dword %0, %1, off sc0 sc1"
               :: "v"(p), "v"(v) : "memory");
}
__device__ __forceinline__ void store_u64_coh(void* p, unsigned long long v) {
  asm volatile("global_store_dwordx2 %0, %1, off sc0 sc1"
               :: "v"(p), "v"(v) : "memory");
}

// async global->LDS, 16B per lane. LDS dest must be wave-uniform base;
// lanes deposit at base + lane*16 (guide section 5 caveat).
typedef __attribute__((address_space(3))) unsigned int* lds_u32p;
typedef const __attribute__((address_space(1))) unsigned int* glb_u32p;
__device__ __forceinline__ void async16(void* lds, const void* g) {
  __builtin_amdgcn_global_load_lds(
      (glb_u32p)(unsigned long long)g,
      (lds_u32p)(unsigned int)(unsigned long long)lds, 16, 0, 0);
}

// ---------------- fused prep kernel ----------------
// Range-partitioned single kernel (9216 blocks x 256):
//   [0, 1310720)        : transpose 5x [512][512] fp32 -> bf16 B^T slabs
//   [1310720, 2097152)  : hidden weights -> MFMA-fragment Whf
//   [2097152, 2359296)  : w0act rows, gib, WoutT, hbuf
// Last block additionally runs the self-contained dones-dtype probe.

__global__ __launch_bounds__(256) void k_prep(
    const float* __restrict__ w0, const float* __restrict__ w1,
    const float* __restrict__ wir, const float* __restrict__ wiz,
    const float* __restrict__ win,
    const float* __restrict__ whr, const float* __restrict__ whz,
    const float* __restrict__ whn,
    const float* __restrict__ bir, const float* __restrict__ biz,
    const float* __restrict__ bin, const float* __restrict__ wout,
    const float* __restrict__ hidden, const int* __restrict__ dI,
    unsigned short* __restrict__ W0at, unsigned short* __restrict__ W1t,
    unsigned short* __restrict__ Wit, unsigned short* __restrict__ Whf,
    unsigned short* __restrict__ w0act, float* __restrict__ gib,
    unsigned short* __restrict__ WoutT, unsigned short* __restrict__ hbuf,
    unsigned int* __restrict__ flag) {
  int i = blockIdx.x * 256 + threadIdx.x;
  if (i < 1310720) {
    int o = i & 262143, z = i >> 18;  // z: 0=w0, 1=w1, 2..4=wir/wiz/win
    int n = o >> 9, k = o & 511;
    const float* s = (z == 0) ? w0 : (z == 1) ? w1 : (z == 2) ? wir
                   : (z == 3) ? wiz : win;
    unsigned short b = f2bf(s[k * 512 + n]);
    if (z == 0) W0at[o] = b;
    else if (z == 1) W1t[o] = b;
    else Wit[(size_t)(z - 2) * 262144 + o] = b;
  } else if (i < 2097152) {
    int j = i - 1310720;  // < 786432
    int k = j / 1536, n = j - k * 1536;
    const float* s = (n < 512) ? whr : (n < 1024) ? whz : whn;
    Whf[((size_t)(k >> 3) * 1536 + n) * 8 + (k & 7)] = f2bf(s[k * 512 + (n & 511)]);
  } else {
    int j = i - 2097152;  // < 262144
    if (j < 9216) {
      int a = j >> 9, n = j & 511;
      w0act[j] = f2bf(w0[(512 + a) * 512 + n]);
    }
    if (j < 1536)
      gib[j] = (j < 512) ? bir[j] : (j < 1024) ? biz[j - 512] : bin[j - 1024];
    if (j < 32768) {
      int n = j >> 9, k = j & 511;
      WoutT[j] = f2bf(n < AD ? wout[k * AD + n] : 0.f);
    }
    hbuf[j] = f2bf(hidden[j]);
  }
  // dones dtype probe (last block, self-contained: no pre-zeroed flag).
  // First 64KB viewed as int32: int32 bools are only {0,1}; packed
  // byte-bools produce values with bits above bit0.
  if (blockIdx.x == 9215) {
    __shared__ int wany[4];
    int t = threadIdx.x;
    int any = 0;
#pragma unroll 8
    for (int v = 0; v < 64; ++v) any |= dI[t * 64 + v] & 0xFFFFFFFE;
    unsigned long long b = __ballot(any != 0);
    if ((t & 63) == 0) wany[t >> 6] = (b != 0ull) ? 1 : 0;
    __syncthreads();
    if (t == 0) *flag = (unsigned int)(wany[0] | wany[1] | wany[2] | wany[3]);
  }
}

// zero the spread flag array (lives in bufA, dead after the gin GEMM)
__global__ __launch_bounds__(256) void k_zero(unsigned int* __restrict__ p) {
  int i = (blockIdx.x * 256 + threadIdx.x) * 4;
  if (i < READY_U32) *(uint4v*)(p + i) = (uint4v){0u, 0u, 0u, 0u};
}

// ---------------- fused encoder GEMM: 128 rows x full 512 cols per block ----
// 512 threads = 8 waves (2M x 4N); per wave 64 rows x 128 cols = 4x8 MFMA
// tiles; acc 128 VGPR. A staged once/block, B panel once/block,
// single-buffered, BK=64, 8 k-iterations.
// MODE 0: layer0  (A = obs fp32 staged directly, converted to bf16 at
//                  fragment load (RNE, identical numerics to old conv);
//                  +bias +w0act[act] gather, LN+ReLU, write bf16)
// MODE 1: layer1  (A bf16; +bias, LN+ReLU, write bf16)
// MODE 2: gin gate g=blockIdx.y (+gib bias, scan-blocked write for k_gru)

template <int MODE>
__global__ __launch_bounds__(512, 1) void k_enc(
    const unsigned short* __restrict__ Ab,   // MODE0: actually const float*
    const unsigned short* __restrict__ Btb,  // [N][512] bf16 (MODE2: slabs)
    unsigned short* __restrict__ Cb,
    const float* __restrict__ bias,          // (MODE2: gib[1536])
    const float* __restrict__ lnS, const float* __restrict__ lnB,
    const unsigned short* __restrict__ gW,   // [18][512] bf16 (MODE0)
    const int* __restrict__ acts) {
  __shared__ __align__(16) unsigned char AsRaw[MODE == 0 ? 32768 : 16384];
  __shared__ unsigned short Bs[32768];   // [8 ch][512 n][8]  64KB
  __shared__ float part[128][4][2];      // row partials per N-wave (4KB)
  __shared__ float stats[128][2];        // mean, rstd (1KB)
  float* Asf = (float*)AsRaw;
  unsigned short* Ash = (unsigned short*)AsRaw;

  const int tid = threadIdx.x, wave = tid >> 6, lane = tid & 63;
  const int quad = lane >> 4, l15 = lane & 15;
  const int wm = wave >> 2, wn = wave & 3;
  const int m0 = blockIdx.x * 128;
  const int g = (MODE == 2) ? blockIdx.y : 0;
  const unsigned short* Bt = Btb + (size_t)g * 262144;
  const float* bi = bias + g * 512;

  float4v acc[4][8];
#pragma unroll
  for (int a = 0; a < 4; ++a)
#pragma unroll
    for (int b = 0; b < 8; ++b) acc[a][b] = (float4v){0.f, 0.f, 0.f, 0.f};

  for (int k0 = 0; k0 < 512; k0 += 64) {
    if constexpr (MODE == 0) {
      // A fp32: 2048 16B units = [8 ch][128 m][2 half], 4/thread
      const float* Af = (const float*)Ab;
#pragma unroll
      for (int r = 0; r < 4; ++r) {
        int u = r * 512 + tid;
        int ch = u >> 8, rem = u & 255, mm = rem >> 1, half = rem & 1;
        async16(&Asf[(size_t)(r * 512 + wave * 64) * 4],
                Af + (size_t)(m0 + mm) * 512 + k0 + ch * 8 + half * 4);
      }
    } else {
      // A bf16: 1024 16B units = [8 ch][128 m], 2/thread
#pragma unroll
      for (int r = 0; r < 2; ++r) {
        int u = r * 512 + tid;
        int ch = u >> 7, mm = u & 127;
        async16(&Ash[(size_t)(r * 512 + wave * 64) * 8],
                Ab + (size_t)(m0 + mm) * 512 + k0 + ch * 8);
      }
    }
#pragma unroll
    for (int r = 0; r < 8; ++r) {      // B: 4096 units, 8/thread
      int u = r * 512 + tid;
      int ch = u >> 9, nn = u & 511;
      async16(&Bs[(size_t)(r * 512 + wave * 64) * 8],
              Bt + (size_t)nn * 512 + k0 + ch * 8);
    }
    __syncthreads();  // compiler drains vmcnt before s_barrier
#pragma unroll
    for (int kk = 0; kk < 2; ++kk) {
      short8 afr[4], bfr[8];
#pragma unroll
      for (int mi = 0; mi < 4; ++mi) {
        int mrow = wm * 64 + mi * 16 + l15;
        if constexpr (MODE == 0) {
          const float* ap = &Asf[(size_t)((kk * 4 + quad) * 128 + mrow) * 8];
          float4v lo = *(const float4v*)ap;
          float4v hi = *(const float4v*)(ap + 4);
          short8 f;
#pragma unroll
          for (int j = 0; j < 4; ++j) {
            f[j] = (short)f2bf(lo[j]);
            f[j + 4] = (short)f2bf(hi[j]);
          }
          afr[mi] = f;
        } else {
          afr[mi] = *(const short8*)
              &Ash[(size_t)((kk * 4 + quad) * 128 + mrow) * 8];
        }
      }
#pragma unroll
      for (int ni = 0; ni < 8; ++ni)
        bfr[ni] = *(const short8*)
            &Bs[((kk * 4 + quad) * 512 + wn * 128 + ni * 16 + l15) * 8];
#pragma unroll
      for (int mi = 0; mi < 4; ++mi)
#pragma unroll
        for (int ni = 0; ni < 8; ++ni)
          acc[mi][ni] = __builtin_amdgcn_mfma_f32_16x16x32_bf16(
              afr[mi], bfr[ni], acc[mi][ni], 0, 0, 0);
    }
    __syncthreads();
  }

  // bias (+one-hot gather) in fp32, into acc
  float bcol[8];
#pragma unroll
  for (int ni = 0; ni < 8; ++ni) bcol[ni] = bi[wn * 128 + ni * 16 + l15];
#pragma unroll
  for (int mi = 0; mi < 4; ++mi)
#pragma unroll
    for (int i = 0; i < 4; ++i) {
      int row = m0 + wm * 64 + mi * 16 + quad * 4 + i;
      int arow = (MODE == 0) ? acts[row] : 0;
#pragma unroll
      for (int ni = 0; ni < 8; ++ni) {
        float v = acc[mi][ni][i] + bcol[ni];
        if (MODE == 0) v += bf2f(gW[arow * 512 + wn * 128 + ni * 16 + l15]);
        acc[mi][ni][i] = v;
      }
    }

  if (MODE <= 1) {
    // ---- fused LayerNorm + ReLU (fp32 accs) ----
#pragma unroll
    for (int mi = 0; mi < 4; ++mi)
#pragma unroll
      for (int i = 0; i < 4; ++i) {
        float s = 0.f, q = 0.f;
#pragma unroll
        for (int ni = 0; ni < 8; ++ni) {
          float v = acc[mi][ni][i];
          s += v; q += v * v;
        }
#pragma unroll
        for (int d = 1; d < 16; d <<= 1) {
          s += __shfl_xor(s, d, 64);
          q += __shfl_xor(q, d, 64);
        }
        if (l15 == 0) {
          int rowl = wm * 64 + mi * 16 + quad * 4 + i;
          part[rowl][wn][0] = s;
          part[rowl][wn][1] = q;
        }
      }
    __syncthreads();
    if (tid < 128) {
      float s = part[tid][0][0] + part[tid][1][0] + part[tid][2][0] + part[tid][3][0];
      float q = part[tid][0][1] + part[tid][1][1] + part[tid][2][1] + part[tid][3][1];
      float mean = s * (1.f / 512.f);
      float var = fmaxf(q * (1.f / 512.f) - mean * mean, 0.f);
      stats[tid][0] = mean;
      stats[tid][1] = rsqrtf(var + 1e-6f);
    }
    __syncthreads();
    float sc8[8], cb8[8];
#pragma unroll
    for (int ni = 0; ni < 8; ++ni) {
      int col = wn * 128 + ni * 16 + l15;
      sc8[ni] = lnS[col];
      cb8[ni] = lnB[col];
    }
#pragma unroll
    for (int mi = 0; mi < 4; ++mi)
#pragma unroll
      for (int i = 0; i < 4; ++i) {
        int rowl = wm * 64 + mi * 16 + quad * 4 + i;
        float mean = stats[rowl][0], rstd = stats[rowl][1];
        int row = m0 + rowl;
#pragma unroll
        for (int ni = 0; ni < 8; ++ni) {
          int col = wn * 128 + ni * 16 + l15;
          float v = fmaxf((acc[mi][ni][i] - mean) * rstd * sc8[ni] + cb8[ni], 0.f);
          Cb[(size_t)row * 512 + col] = f2bf(v);
        }
      }
  } else {
    // ---- MODE 2: scan-blocked write for k_gru ----
#pragma unroll
    for (int mi = 0; mi < 4; ++mi)
#pragma unroll
      for (int i = 0; i < 4; ++i) {
        int row = m0 + wm * 64 + mi * 16 + quad * 4 + i;
        int t = row >> 9, b = row & 511;
#pragma unroll
        for (int ni = 0; ni < 8; ++ni) {
          int c = wn * 128 + ni * 16 + l15;
          size_t dst = ((size_t)((b >> 6) * 32 + (c >> 4)) * 128 + t) * 3072
                     + (size_t)g * 1024 + (b & 63) * 16 + (c & 15);
          Cb[dst] = f2bf(acc[mi][ni][i]);
        }
      }
  }
}

// ---------------- phase B: GRU scan (untouched, verified 517-519us) ---------
// 256 blocks (8 row-groups x 32 col-chunks) x 256 threads, 1 block/CU (LDS).
// MFMA swapped (W as A, h as B): each thread owns (1 row, 4 cols) of D ->
// one 8B coherent h store, one dones byte, float4 outh store. gin staged
// from its scan-blocked layout: per chunk = 48KB CONTIGUOUS per block,
// 12 async16/thread every 8 steps, double-buffered; dones staged once.
// Handoff: producer sc0sc1 write-through h + vmcnt(0)-drained barrier +
// sc0sc1 flag publish; consumer sc0sc1 flag poll + plain fresh-region
// h loads (R5 protocol, verified).

__global__ __launch_bounds__(256, 1) void k_gru(
    const unsigned short* __restrict__ Whf, const unsigned short* __restrict__ gin,
    const float* __restrict__ bhn, const int* __restrict__ dI,
    const unsigned char* __restrict__ dB, const unsigned int* __restrict__ flag,
    const unsigned short* __restrict__ hbuf, unsigned short* __restrict__ ybuf,
    float* __restrict__ outh, unsigned int* __restrict__ ready) {
  // LDS: gin [2 bufs][GSTEPS][3 gates][64 rows][16 cols] bf16 = 96KB
  //      dones [128 steps][64 rows] bytes = 8KB       (total 104KB < 160KB)
  __shared__ __align__(16) unsigned short gin_lds[2][GSTEPS * 3 * 64 * 16];
  __shared__ unsigned char d_lds[TT * 64];

  const int tid = threadIdx.x, wave = tid >> 6, lane = tid & 63;
  const int quad = lane >> 4, l15 = lane & 15;
  const int rt = blockIdx.x & 7;    // row group (64 rows)
  const int cc = blockIdx.x >> 3;   // col chunk (16 cols per gate), 0..31
  const int r0b = rt * 64;          // block's first batch row
  const int rowb = wave * 16 + l15; // thread's row within block
  const int row = r0b + rowb;       // global batch row
  const int c0 = cc * 16 + quad * 4;  // thread's first gate-col (per gate)
  const int bytemode = (int)(*flag);
  const float4v bhn4 = *(const float4v*)(bhn + c0);

  // this block's contiguous gin stream: base of [t][g][64][16] blocks
  const unsigned short* gsrc = gin + (size_t)(rt * 32 + cc) * 128 * 3072;

  // chunk staging: GSTEPS*3072 elements contiguous = 3072 16B units,
  // 12 per thread, straight-line copy
  auto stage_gin = [&](int buf, int t0) {
    const unsigned short* src = gsrc + (size_t)t0 * 3072;
#pragma unroll
    for (int r = 0; r < 12; ++r) {
      async16(&gin_lds[buf][(size_t)(r * 256 + wave * 64) * 8],
              src + (size_t)(r * 256 + tid) * 8);
    }
  };

  // prologue: stage chunk 0, stage all dones, load weights + hprev
  stage_gin(0, 0);
#pragma unroll
  for (int r = 0; r < 32; ++r) {
    int idx = r * 256 + tid;         // idx = t*64 + rowInBlock
    int t = idx >> 6, rr = idx & 63;
    int gidx = t * 512 + r0b + rr;
    d_lds[idx] = bytemode ? dB[gidx] : (unsigned char)(dI[gidx] != 0);
  }

  // weight-stationary A fragments: [gate][k-step]
  short8 bw[3][16];
#pragma unroll
  for (int kc = 0; kc < 16; ++kc)
#pragma unroll
    for (int g = 0; g < 3; ++g) {
      size_t u = (size_t)(kc * 4 + quad) * 1536 + (g * 512 + cc * 16 + l15);
      bw[g][kc] = *(const short8*)(Whf + u * 8);
    }

  // own h carried in registers (fp32): 4 consecutive cols of own row
  float hprev[4];
  {
    unsigned long long w = *(const unsigned long long*)(hbuf + (size_t)row * 512 + c0);
#pragma unroll
    for (int i = 0; i < 4; ++i) hprev[i] = bf2f((unsigned short)(w >> (16 * i)));
  }

  __syncthreads();  // drains staging vmcnt + dones ds_writes

  for (int t = 0; t < TT; ++t) {
    if (t > 0) {
      if (wave == 0) {
        // 32 lanes poll 32 per-producer flags (128B apart) in parallel
        const unsigned int* fp =
            ready + (((size_t)rt * 130 + t) * 32 + (lane & 31)) * FSTRIDE;
        unsigned int v;
        int guard = 0;
        do {
          v = load_u32_coh(fp);
        } while (__ballot(v == 0u) != 0ull && ++guard < (1 << 22));
      }
      __syncthreads();
      asm volatile("" ::: "memory");  // no hoisting h loads above the wait
    }

    // B fragments: h rows, plain cached loads from per-step-fresh region
    const unsigned short* hsrc =
        (t == 0) ? hbuf : ybuf + (size_t)(t - 1) * 262144;
    const unsigned short* ap = hsrc + (size_t)row * 512 + quad * 8;
    short8 af[16];
#pragma unroll
    for (int kc = 0; kc < 16; ++kc) af[kc] = *(const short8*)(ap + kc * 32);

    const int dd = (int)d_lds[(t << 6) + rowb];
    if (dd) {
      const short8 z8 = {0, 0, 0, 0, 0, 0, 0, 0};
#pragma unroll
      for (int kc = 0; kc < 16; ++kc) af[kc] = z8;
    }

    // stage next chunk (drained by this step's ending __syncthreads)
    if ((t & (GSTEPS - 1)) == 0 && t + GSTEPS < TT)
      stage_gin(((t >> 3) + 1) & 1, t + GSTEPS);

    // gin from LDS: 3x ds_read_b64 (4 consecutive cols per gate)
    const int sl = t & (GSTEPS - 1), bufc = (t >> 3) & 1;
    float gr[4], gz[4], gn[4];
    {
      const unsigned short* gl =
          &gin_lds[bufc][((size_t)(sl * 3) * 64 + rowb) * 16 + quad * 4];
      unsigned long long w0 = *(const unsigned long long*)(gl);
      unsigned long long w1 = *(const unsigned long long*)(gl + 1024);
      unsigned long long w2 = *(const unsigned long long*)(gl + 2048);
#pragma unroll
      for (int i = 0; i < 4; ++i) {
        gr[i] = bf2f((unsigned short)(w0 >> (16 * i)));
        gz[i] = bf2f((unsigned short)(w1 >> (16 * i)));
        gn[i] = bf2f((unsigned short)(w2 >> (16 * i)));
      }
    }

    float4v a0 = {0.f, 0.f, 0.f, 0.f}, a1 = a0, a2 = a0;
#pragma unroll
    for (int kc = 0; kc < 16; ++kc) {
      a0 = __builtin_amdgcn_mfma_f32_16x16x32_bf16(bw[0][kc], af[kc], a0, 0, 0, 0);
      a1 = __builtin_amdgcn_mfma_f32_16x16x32_bf16(bw[1][kc], af[kc], a1, 0, 0, 0);
      a2 = __builtin_amdgcn_mfma_f32_16x16x32_bf16(bw[2][kc], af[kc], a2, 0, 0, 0);
    }

    unsigned short* ydst = ybuf + (size_t)t * 262144;
    float hv[4];
#pragma unroll
    for (int i = 0; i < 4; ++i) {
      float hold = dd ? 0.f : hprev[i];
      float r = 1.f / (1.f + __expf(-(a0[i] + gr[i])));
      float z = 1.f / (1.f + __expf(-(a1[i] + gz[i])));
      float npre = gn[i] + r * (a2[i] + bhn4[i]);
      float n = 1.f - 2.f / (1.f + __expf(2.f * npre));  // tanh, inf-safe
      hv[i] = (1.f - z) * n + z * hold;
      hprev[i] = hv[i];
    }
    {
      unsigned long long pk = (unsigned long long)f2bf(hv[0])
          | ((unsigned long long)f2bf(hv[1]) << 16)
          | ((unsigned long long)f2bf(hv[2]) << 32)
          | ((unsigned long long)f2bf(hv[3]) << 48);
      // write-through to coherence point (IC): next step's cross-XCD input
      store_u64_coh(ydst + (size_t)row * 512 + c0, pk);
    }
    if (t == TT - 1) {
      float4v o = {hv[0], hv[1], hv[2], hv[3]};
      *(float4v*)(outh + (size_t)row * 512 + c0) = o;
    }

    __syncthreads();  // s_waitcnt vmcnt(0) before s_barrier: h at IC
    if (tid == 0)
      store_u32_coh(&ready[(((size_t)rt * 130 + t + 1) * 32 + cc) * FSTRIDE], 1u);
  }
}

// ---------------- phase C: q = y @ w_out + b_out (N padded to 64) -----------
// BK=64: 8 k-iterations, 2x8 MFMA per iteration.

__global__ __launch_bounds__(256) void k_qout(
    const unsigned short* __restrict__ Yb, const unsigned short* __restrict__ Wt,
    const float* __restrict__ bout, float* __restrict__ Q) {
  __shared__ unsigned short As[8192];
  __shared__ unsigned short Bs[4096];
  const int tid = threadIdx.x, wave = tid >> 6, lane = tid & 63;
  const int quad = lane >> 4, l15 = lane & 15;
  const int m0 = blockIdx.x * 128;

  float4v acc[2][4];
#pragma unroll
  for (int a = 0; a < 2; ++a)
#pragma unroll
    for (int b = 0; b < 4; ++b) acc[a][b] = (float4v){0.f, 0.f, 0.f, 0.f};

  for (int k0 = 0; k0 < 512; k0 += 64) {
#pragma unroll
    for (int r = 0; r < 4; ++r) {
      int u = r * 256 + wave * 64 + lane;
      int ch = u >> 7, mm = u & 127;
      async16(&As[(size_t)(r * 256 + wave * 64) * 8],
              Yb + (size_t)(m0 + mm) * 512 + k0 + ch * 8);
    }
#pragma unroll
    for (int r = 0; r < 2; ++r) {
      int u = r * 256 + wave * 64 + lane;
      int ch = u >> 6, nn = u & 63;
      async16(&Bs[(size_t)(r * 256 + wave * 64) * 8],
              Wt + (size_t)nn * 512 + k0 + ch * 8);
    }
    __syncthreads();
#pragma unroll
    for (int kk = 0; kk < 2; ++kk) {
      short8 afr[2], bfr[4];
#pragma unroll
      for (int mi = 0; mi < 2; ++mi)
        afr[mi] = *(const short8*)
            &As[((kk * 4 + quad) * 128 + wave * 32 + mi * 16 + l15) * 8];
#pragma unroll
      for (int ni = 0; ni < 4; ++ni)
        bfr[ni] = *(const short8*)
            &Bs[((kk * 4 + quad) * 64 + ni * 16 + l15) * 8];
#pragma unroll
      for (int mi = 0; mi < 2; ++mi)
#pragma unroll
        for (int ni = 0; ni < 4; ++ni)
          acc[mi][ni] = __builtin_amdgcn_mfma_f32_16x16x32_bf16(
              afr[mi], bfr[ni], acc[mi][ni], 0, 0, 0);
    }
    __syncthreads();
  }
#pragma unroll
  for (int mi = 0; mi < 2; ++mi)
#pragma unroll
    for (int ni = 0; ni < 4; ++ni)
#pragma unroll
      for (int i = 0; i < 4; ++i) {
        int row = m0 + wave * 32 + mi * 16 + quad * 4 + i;
        int colq = ni * 16 + l15;
        if (colq < AD) Q[(size_t)row * AD + colq] = acc[mi][ni][i] + bout[colq];
      }
}

// ---------------- launch ----------------------------------------------------

extern "C" void kernel_launch(void* const* d_in, const int* in_sizes, int n_in,
                              void* d_out, int out_size, void* d_ws,
                              size_t ws_size, hipStream_t stream) {
  const float* hidden = (const float*)d_in[0];
  const float* obs = (const float*)d_in[1];
  const void* dones = d_in[2];
  const int* acts = (const int*)d_in[3];
  const float* w0 = (const float*)d_in[4];
  const float* b0 = (const float*)d_in[5];
  const float* ln0s = (const float*)d_in[6];
  const float* ln0b = (const float*)d_in[7];
  const float* w1 = (const float*)d_in[8];
  const float* b1 = (const float*)d_in[9];
  const float* ln1s = (const float*)d_in[10];
  const float* ln1b = (const float*)d_in[11];
  const float* wir = (const float*)d_in[12];
  const float* bir = (const float*)d_in[13];
  const float* wiz = (const float*)d_in[14];
  const float* biz = (const float*)d_in[15];
  const float* win = (const float*)d_in[16];
  const float* bin = (const float*)d_in[17];
  const float* whr = (const float*)d_in[18];
  const float* whz = (const float*)d_in[19];
  const float* whn = (const float*)d_in[20];
  const float* bhn = (const float*)d_in[21];
  const float* wout = (const float*)d_in[22];
  const float* bout = (const float*)d_in[23];

  char* ws = (char*)d_ws;
  unsigned short* bufA = (unsigned short*)(ws);                   // 64MB: x2 -> [ready]
  unsigned short* bufB = (unsigned short*)(ws + 67108864ULL);     // 64MB: x1 -> y/h
  unsigned short* gin = (unsigned short*)(ws + 134217728ULL);     // 192MB (scan-blocked)
  char* D = ws + 134217728ULL + 201326592ULL;
  unsigned short* W0at = (unsigned short*)(D);                    // 512KB
  unsigned short* W1t = (unsigned short*)(D + 524288);            // 512KB
  unsigned short* Wit = (unsigned short*)(D + 1048576);           // 1.5MB
  unsigned short* Whf = (unsigned short*)(D + 2621440);           // 1.5MB
  unsigned short* WoutT = (unsigned short*)(D + 4194304);         // 64KB
  unsigned short* w0act = (unsigned short*)(D + 4259840);         // 32KB
  float* gib = (float*)(D + 4292608);                             // 8KB
  unsigned short* hbuf = (unsigned short*)(D + 4300800);          // 512KB init h
  unsigned int* flag = (unsigned int*)(D + 4825088);              // 4B dones-dtype
  unsigned int* ready = (unsigned int*)ws;                        // 4.26MB in bufA

  (void)in_sizes; (void)n_in; (void)out_size; (void)ws_size;

  // all weight/misc prep + self-contained dones-dtype probe: ONE kernel
  k_prep<<<9216, 256, 0, stream>>>(w0, w1, wir, wiz, win, whr, whz, whn,
                                   bir, biz, bin, wout, hidden,
                                   (const int*)dones, W0at, W1t, Wit, Whf,
                                   w0act, gib, WoutT, hbuf, flag);
  // fused encoder: GEMM+bias(+gather)+LN+ReLU per layer; obs fp32 direct
  k_enc<0><<<512, 512, 0, stream>>>((const unsigned short*)obs, W0at, bufB,
                                    b0, ln0s, ln0b, w0act, acts);
  k_enc<1><<<512, 512, 0, stream>>>(bufB, W1t, bufA, b1, ln1s, ln1b,
                                    nullptr, nullptr);
  // GRU input projections (biases fused), written scan-blocked; 1 gate per y
  k_enc<2><<<dim3(512, 3), 512, 0, stream>>>(bufA, Wit, gin, gib, nullptr,
                                             nullptr, nullptr, nullptr);
  // bufA is now dead: zero the spread flag array there
  k_zero<<<1041, 256, 0, stream>>>(ready);
  // sequential scan; writes new_hidden to d_out[0:262144] and y/h to bufB
  k_gru<<<256, 256, 0, stream>>>(Whf, gin, bhn, (const int*)dones,
                                 (const unsigned char*)dones, flag, hbuf, bufB,
                                 (float*)d_out, ready);
  // output head -> d_out[262144:]
  k_qout<<<512, 256, 0, stream>>>(bufB, WoutT, bout, (float*)d_out + 262144);
}

// Round 10
// 1216.485 us; speedup vs baseline: 1.0316x; 1.0037x over previous
//
#include <hip/hip_runtime.h>
#include <cstdint>
#include <cstddef>

// RNNQNetwork: fused MLP encoder (row-complete MFMA GEMM + in-epilogue
// LayerNorm+ReLU, obs fp32 consumed directly) -> 128-step GRU scan
// (weight-stationary distributed GEMM, sc0sc1 handoff) -> output head GEMM.
//
// R14 = R13 resubmitted (3rd "container failed twice" infra event; R7->R8
// and R10->R11 both passed unchanged, and the bounds/LDS/MFMA-layout audit
// found no GPU-fault surface). R13's change: k_gru grid re-partitioned
// 8x32(64rx16c) -> 16x16(32rx32c): consumers per h-tile 16 (was 32),
// unique-h per consumer 32KB (was 64), producer fan-in 16, per-step
// handoff traffic ~halved. Same 256 blocks x 256 threads, same verified
// sc0sc1 protocol, same per-step gin bytes (staging machinery identical);
// only index formulas + k_enc<2>'s blocked-write formula changed.

#define TT 128
#define BBATCH 512
#define HH 512
#define MM 65536   // T*B
#define AD 18
#define GSTEPS 8   // gin staging chunk (steps per LDS buffer)
#define FSTRIDE 32 // u32s between flags (128B: one line per flag)
#define READY_U32 1064960  // ((16*130)*16) flags * FSTRIDE

typedef __attribute__((ext_vector_type(8))) short short8;
typedef __attribute__((ext_vector_type(4))) float float4v;
typedef __attribute__((ext_vector_type(4))) unsigned int uint4v;

__device__ __forceinline__ unsigned short f2bf(float f) {
  union { float f; unsigned int u; } v; v.f = f;
  unsigned int r = v.u + 0x7fffu + ((v.u >> 16) & 1u);  // RNE
  return (unsigned short)(r >> 16);
}
__device__ __forceinline__ float bf2f(unsigned short h) {
  union { unsigned int u; float f; } v; v.u = ((unsigned int)h) << 16;
  return v.f;
}

// per-access coherent (coherence-point) ops: sc0 sc1 = device-scope, no fence
__device__ __forceinline__ unsigned int load_u32_coh(const unsigned int* p) {
  unsigned int v;
  asm volatile("global_load_dword %0, %1, off sc0 sc1\n\ts_waitcnt vmcnt(0)"
               : "=v"(v) : "v"(p) : "memory");
  return v;
}
__device__ __forceinline__ void store_u32_coh(unsigned int* p, unsigned int v) {
  asm volatile("global_store_dword %0, %1, off sc0 sc1"
               :: "v"(p), "v"(v) : "memory");
}
__device__ __forceinline__ void store_u64_coh(void* p, unsigned long long v) {
  asm volatile("global_store_dwordx2 %0, %1, off sc0 sc1"
               :: "v"(p), "v"(v) : "memory");
}

// async global->LDS, 16B per lane. LDS dest must be wave-uniform base;
// lanes deposit at base + lane*16 (guide section 5 caveat).
typedef __attribute__((address_space(3))) unsigned int* lds_u32p;
typedef const __attribute__((address_space(1))) unsigned int* glb_u32p;
__device__ __forceinline__ void async16(void* lds, const void* g) {
  __builtin_amdgcn_global_load_lds(
      (glb_u32p)(unsigned long long)g,
      (lds_u32p)(unsigned int)(unsigned long long)lds, 16, 0, 0);
}

// ---------------- fused prep kernel ----------------
// Range-partitioned single kernel (9216 blocks x 256):
//   [0, 1310720)        : transpose 5x [512][512] fp32 -> bf16 B^T slabs
//   [1310720, 2097152)  : hidden weights -> MFMA-fragment Whf
//   [2097152, 2359296)  : w0act rows, gib, WoutT, hbuf
// Last block additionally runs the self-contained dones-dtype probe.

__global__ __launch_bounds__(256) void k_prep(
    const float* __restrict__ w0, const float* __restrict__ w1,
    const float* __restrict__ wir, const float* __restrict__ wiz,
    const float* __restrict__ win,
    const float* __restrict__ whr, const float* __restrict__ whz,
    const float* __restrict__ whn,
    const float* __restrict__ bir, const float* __restrict__ biz,
    const float* __restrict__ bin, const float* __restrict__ wout,
    const float* __restrict__ hidden, const int* __restrict__ dI,
    unsigned short* __restrict__ W0at, unsigned short* __restrict__ W1t,
    unsigned short* __restrict__ Wit, unsigned short* __restrict__ Whf,
    unsigned short* __restrict__ w0act, float* __restrict__ gib,
    unsigned short* __restrict__ WoutT, unsigned short* __restrict__ hbuf,
    unsigned int* __restrict__ flag) {
  int i = blockIdx.x * 256 + threadIdx.x;
  if (i < 1310720) {
    int o = i & 262143, z = i >> 18;  // z: 0=w0, 1=w1, 2..4=wir/wiz/win
    int n = o >> 9, k = o & 511;
    const float* s = (z == 0) ? w0 : (z == 1) ? w1 : (z == 2) ? wir
                   : (z == 3) ? wiz : win;
    unsigned short b = f2bf(s[k * 512 + n]);
    if (z == 0) W0at[o] = b;
    else if (z == 1) W1t[o] = b;
    else Wit[(size_t)(z - 2) * 262144 + o] = b;
  } else if (i < 2097152) {
    int j = i - 1310720;  // < 786432
    int k = j / 1536, n = j - k * 1536;
    const float* s = (n < 512) ? whr : (n < 1024) ? whz : whn;
    Whf[((size_t)(k >> 3) * 1536 + n) * 8 + (k & 7)] = f2bf(s[k * 512 + (n & 511)]);
  } else {
    int j = i - 2097152;  // < 262144
    if (j < 9216) {
      int a = j >> 9, n = j & 511;
      w0act[j] = f2bf(w0[(512 + a) * 512 + n]);
    }
    if (j < 1536)
      gib[j] = (j < 512) ? bir[j] : (j < 1024) ? biz[j - 512] : bin[j - 1024];
    if (j < 32768) {
      int n = j >> 9, k = j & 511;
      WoutT[j] = f2bf(n < AD ? wout[k * AD + n] : 0.f);
    }
    hbuf[j] = f2bf(hidden[j]);
  }
  // dones dtype probe (last block, self-contained: no pre-zeroed flag).
  if (blockIdx.x == 9215) {
    __shared__ int wany[4];
    int t = threadIdx.x;
    int any = 0;
#pragma unroll 8
    for (int v = 0; v < 64; ++v) any |= dI[t * 64 + v] & 0xFFFFFFFE;
    unsigned long long b = __ballot(any != 0);
    if ((t & 63) == 0) wany[t >> 6] = (b != 0ull) ? 1 : 0;
    __syncthreads();
    if (t == 0) *flag = (unsigned int)(wany[0] | wany[1] | wany[2] | wany[3]);
  }
}

// zero the spread flag array (lives in bufA, dead after the gin GEMM)
__global__ __launch_bounds__(256) void k_zero(unsigned int* __restrict__ p) {
  int i = (blockIdx.x * 256 + threadIdx.x) * 4;
  if (i < READY_U32) *(uint4v*)(p + i) = (uint4v){0u, 0u, 0u, 0u};
}

// ---------------- fused encoder GEMM: 128 rows x full 512 cols per block ----
// MODE 0: layer0 (A = obs fp32 direct; +bias +w0act gather, LN+ReLU)
// MODE 1: layer1 (A bf16; +bias, LN+ReLU)
// MODE 2: gin gate g=blockIdx.y (+gib bias, scan-blocked write for k_gru)

template <int MODE>
__global__ __launch_bounds__(512, 1) void k_enc(
    const unsigned short* __restrict__ Ab,   // MODE0: actually const float*
    const unsigned short* __restrict__ Btb,  // [N][512] bf16 (MODE2: slabs)
    unsigned short* __restrict__ Cb,
    const float* __restrict__ bias,          // (MODE2: gib[1536])
    const float* __restrict__ lnS, const float* __restrict__ lnB,
    const unsigned short* __restrict__ gW,   // [18][512] bf16 (MODE0)
    const int* __restrict__ acts) {
  __shared__ __align__(16) unsigned char AsRaw[MODE == 0 ? 32768 : 16384];
  __shared__ unsigned short Bs[32768];   // [8 ch][512 n][8]  64KB
  __shared__ float part[128][4][2];      // row partials per N-wave (4KB)
  __shared__ float stats[128][2];        // mean, rstd (1KB)
  float* Asf = (float*)AsRaw;
  unsigned short* Ash = (unsigned short*)AsRaw;

  const int tid = threadIdx.x, wave = tid >> 6, lane = tid & 63;
  const int quad = lane >> 4, l15 = lane & 15;
  const int wm = wave >> 2, wn = wave & 3;
  const int m0 = blockIdx.x * 128;
  const int g = (MODE == 2) ? blockIdx.y : 0;
  const unsigned short* Bt = Btb + (size_t)g * 262144;
  const float* bi = bias + g * 512;

  float4v acc[4][8];
#pragma unroll
  for (int a = 0; a < 4; ++a)
#pragma unroll
    for (int b = 0; b < 8; ++b) acc[a][b] = (float4v){0.f, 0.f, 0.f, 0.f};

  for (int k0 = 0; k0 < 512; k0 += 64) {
    if constexpr (MODE == 0) {
      const float* Af = (const float*)Ab;
#pragma unroll
      for (int r = 0; r < 4; ++r) {
        int u = r * 512 + tid;
        int ch = u >> 8, rem = u & 255, mm = rem >> 1, half = rem & 1;
        async16(&Asf[(size_t)(r * 512 + wave * 64) * 4],
                Af + (size_t)(m0 + mm) * 512 + k0 + ch * 8 + half * 4);
      }
    } else {
#pragma unroll
      for (int r = 0; r < 2; ++r) {
        int u = r * 512 + tid;
        int ch = u >> 7, mm = u & 127;
        async16(&Ash[(size_t)(r * 512 + wave * 64) * 8],
                Ab + (size_t)(m0 + mm) * 512 + k0 + ch * 8);
      }
    }
#pragma unroll
    for (int r = 0; r < 8; ++r) {      // B: 4096 units, 8/thread
      int u = r * 512 + tid;
      int ch = u >> 9, nn = u & 511;
      async16(&Bs[(size_t)(r * 512 + wave * 64) * 8],
              Bt + (size_t)nn * 512 + k0 + ch * 8);
    }
    __syncthreads();  // compiler drains vmcnt before s_barrier
#pragma unroll
    for (int kk = 0; kk < 2; ++kk) {
      short8 afr[4], bfr[8];
#pragma unroll
      for (int mi = 0; mi < 4; ++mi) {
        int mrow = wm * 64 + mi * 16 + l15;
        if constexpr (MODE == 0) {
          const float* ap = &Asf[(size_t)((kk * 4 + quad) * 128 + mrow) * 8];
          float4v lo = *(const float4v*)ap;
          float4v hi = *(const float4v*)(ap + 4);
          short8 f;
#pragma unroll
          for (int j = 0; j < 4; ++j) {
            f[j] = (short)f2bf(lo[j]);
            f[j + 4] = (short)f2bf(hi[j]);
          }
          afr[mi] = f;
        } else {
          afr[mi] = *(const short8*)
              &Ash[(size_t)((kk * 4 + quad) * 128 + mrow) * 8];
        }
      }
#pragma unroll
      for (int ni = 0; ni < 8; ++ni)
        bfr[ni] = *(const short8*)
            &Bs[((kk * 4 + quad) * 512 + wn * 128 + ni * 16 + l15) * 8];
#pragma unroll
      for (int mi = 0; mi < 4; ++mi)
#pragma unroll
        for (int ni = 0; ni < 8; ++ni)
          acc[mi][ni] = __builtin_amdgcn_mfma_f32_16x16x32_bf16(
              afr[mi], bfr[ni], acc[mi][ni], 0, 0, 0);
    }
    __syncthreads();
  }

  // bias (+one-hot gather) in fp32, into acc
  float bcol[8];
#pragma unroll
  for (int ni = 0; ni < 8; ++ni) bcol[ni] = bi[wn * 128 + ni * 16 + l15];
#pragma unroll
  for (int mi = 0; mi < 4; ++mi)
#pragma unroll
    for (int i = 0; i < 4; ++i) {
      int row = m0 + wm * 64 + mi * 16 + quad * 4 + i;
      int arow = (MODE == 0) ? acts[row] : 0;
#pragma unroll
      for (int ni = 0; ni < 8; ++ni) {
        float v = acc[mi][ni][i] + bcol[ni];
        if (MODE == 0) v += bf2f(gW[arow * 512 + wn * 128 + ni * 16 + l15]);
        acc[mi][ni][i] = v;
      }
    }

  if (MODE <= 1) {
    // ---- fused LayerNorm + ReLU (fp32 accs) ----
#pragma unroll
    for (int mi = 0; mi < 4; ++mi)
#pragma unroll
      for (int i = 0; i < 4; ++i) {
        float s = 0.f, q = 0.f;
#pragma unroll
        for (int ni = 0; ni < 8; ++ni) {
          float v = acc[mi][ni][i];
          s += v; q += v * v;
        }
#pragma unroll
        for (int d = 1; d < 16; d <<= 1) {
          s += __shfl_xor(s, d, 64);
          q += __shfl_xor(q, d, 64);
        }
        if (l15 == 0) {
          int rowl = wm * 64 + mi * 16 + quad * 4 + i;
          part[rowl][wn][0] = s;
          part[rowl][wn][1] = q;
        }
      }
    __syncthreads();
    if (tid < 128) {
      float s = part[tid][0][0] + part[tid][1][0] + part[tid][2][0] + part[tid][3][0];
      float q = part[tid][0][1] + part[tid][1][1] + part[tid][2][1] + part[tid][3][1];
      float mean = s * (1.f / 512.f);
      float var = fmaxf(q * (1.f / 512.f) - mean * mean, 0.f);
      stats[tid][0] = mean;
      stats[tid][1] = rsqrtf(var + 1e-6f);
    }
    __syncthreads();
    float sc8[8], cb8[8];
#pragma unroll
    for (int ni = 0; ni < 8; ++ni) {
      int col = wn * 128 + ni * 16 + l15;
      sc8[ni] = lnS[col];
      cb8[ni] = lnB[col];
    }
#pragma unroll
    for (int mi = 0; mi < 4; ++mi)
#pragma unroll
      for (int i = 0; i < 4; ++i) {
        int rowl = wm * 64 + mi * 16 + quad * 4 + i;
        float mean = stats[rowl][0], rstd = stats[rowl][1];
        int row = m0 + rowl;
#pragma unroll
        for (int ni = 0; ni < 8; ++ni) {
          int col = wn * 128 + ni * 16 + l15;
          float v = fmaxf((acc[mi][ni][i] - mean) * rstd * sc8[ni] + cb8[ni], 0.f);
          Cb[(size_t)row * 512 + col] = f2bf(v);
        }
      }
  } else {
    // ---- MODE 2: scan-blocked write for the 16x16 (32r x 32c) k_gru grid:
    // blk = (b>>5)*16 + (c>>5); [blk][t][g][b&31][c&31]
#pragma unroll
    for (int mi = 0; mi < 4; ++mi)
#pragma unroll
      for (int i = 0; i < 4; ++i) {
        int row = m0 + wm * 64 + mi * 16 + quad * 4 + i;
        int t = row >> 9, b = row & 511;
#pragma unroll
        for (int ni = 0; ni < 8; ++ni) {
          int c = wn * 128 + ni * 16 + l15;
          size_t dst = ((size_t)((b >> 5) * 16 + (c >> 5)) * 128 + t) * 3072
                     + (size_t)g * 1024 + (b & 31) * 32 + (c & 31);
          Cb[dst] = f2bf(acc[mi][ni][i]);
        }
      }
  }
}

// ---------------- phase B: GRU scan -----------------------------------------
// 16x16 grid: 256 blocks = 16 row-groups (32 rows) x 16 col-chunks (32
// gate-cols), 256 threads = 4 waves (2 row-waves x 2 col-waves). Each
// thread owns (1 row, 4 cols) per gate. Consumers per h-tile: 16; unique
// h per block: 32KB; fan-in 16. Protocol identical to the verified R5
// path: producer sc0sc1 h write-through + vmcnt(0)-drained barrier +
// sc0sc1 flag publish; consumer sc0sc1 poll + plain h loads from the
// per-step-fresh region. gin staging machinery byte-identical.

__global__ __launch_bounds__(256, 1) void k_gru(
    const unsigned short* __restrict__ Whf, const unsigned short* __restrict__ gin,
    const float* __restrict__ bhn, const int* __restrict__ dI,
    const unsigned char* __restrict__ dB, const unsigned int* __restrict__ flag,
    const unsigned short* __restrict__ hbuf, unsigned short* __restrict__ ybuf,
    float* __restrict__ outh, unsigned int* __restrict__ ready) {
  // LDS: gin [2 bufs][GSTEPS][3 gates][32 rows][32 cols] bf16 = 96KB
  //      dones [128 steps][32 rows] bytes = 4KB       (total 100KB)
  __shared__ __align__(16) unsigned short gin_lds[2][GSTEPS * 3 * 32 * 32];
  __shared__ unsigned char d_lds[TT * 32];

  const int tid = threadIdx.x, wave = tid >> 6, lane = tid & 63;
  const int quad = lane >> 4, l15 = lane & 15;
  const int rt = blockIdx.x & 15;   // row group (32 rows); %8 = XCD under RR
  const int cc = blockIdx.x >> 4;   // col chunk (32 cols per gate), 0..15
  const int r0b = rt * 32;          // block's first batch row
  const int rowb = (wave & 1) * 16 + l15;      // thread's row within block
  const int row = r0b + rowb;                  // global batch row
  const int c0 = cc * 32 + (wave >> 1) * 16 + quad * 4;  // first gate-col
  const int bytemode = (int)(*flag);
  const float4v bhn4 = *(const float4v*)(bhn + c0);

  // this block's contiguous gin stream: [t][g][32 rows][32 cols] blocks
  const unsigned short* gsrc = gin + (size_t)(rt * 16 + cc) * 128 * 3072;

  // chunk staging: GSTEPS*3072 elements contiguous = 3072 16B units,
  // 12 per thread, straight-line copy
  auto stage_gin = [&](int buf, int t0) {
    const unsigned short* src = gsrc + (size_t)t0 * 3072;
#pragma unroll
    for (int r = 0; r < 12; ++r) {
      async16(&gin_lds[buf][(size_t)(r * 256 + wave * 64) * 8],
              src + (size_t)(r * 256 + tid) * 8);
    }
  };

  // prologue: stage chunk 0, stage all dones, load weights + hprev
  stage_gin(0, 0);
#pragma unroll
  for (int r = 0; r < 16; ++r) {
    int idx = r * 256 + tid;         // idx = t*32 + rowInBlock
    int t = idx >> 5, rr = idx & 31;
    int gidx = t * 512 + r0b + rr;
    d_lds[idx] = bytemode ? dB[gidx] : (unsigned char)(dI[gidx] != 0);
  }

  // weight-stationary A fragments: [gate][k-step]; A m-index = gate-col
  short8 bw[3][16];
#pragma unroll
  for (int kc = 0; kc < 16; ++kc)
#pragma unroll
    for (int g = 0; g < 3; ++g) {
      size_t u = (size_t)(kc * 4 + quad) * 1536
               + (g * 512 + cc * 32 + (wave >> 1) * 16 + l15);
      bw[g][kc] = *(const short8*)(Whf + u * 8);
    }

  // own h carried in registers (fp32): 4 consecutive cols of own row
  float hprev[4];
  {
    unsigned long long w = *(const unsigned long long*)(hbuf + (size_t)row * 512 + c0);
#pragma unroll
    for (int i = 0; i < 4; ++i) hprev[i] = bf2f((unsigned short)(w >> (16 * i)));
  }

  __syncthreads();  // drains staging vmcnt + dones ds_writes

  for (int t = 0; t < TT; ++t) {
    if (t > 0) {
      if (wave == 0) {
        // 64 lanes poll the 16 per-producer flags (4x duplicated; 128B apart)
        const unsigned int* fp =
            ready + (((size_t)rt * 130 + t) * 16 + (lane & 15)) * FSTRIDE;
        unsigned int v;
        int guard = 0;
        do {
          v = load_u32_coh(fp);
        } while (__ballot(v == 0u) != 0ull && ++guard < (1 << 22));
      }
      __syncthreads();
      asm volatile("" ::: "memory");  // no hoisting h loads above the wait
    }

    // B fragments: h rows (n-index = own row), plain cached loads from
    // per-step-fresh region (L1 serves the col-wave overlap)
    const unsigned short* hsrc =
        (t == 0) ? hbuf : ybuf + (size_t)(t - 1) * 262144;
    const unsigned short* ap = hsrc + (size_t)row * 512 + quad * 8;
    short8 af[16];
#pragma unroll
    for (int kc = 0; kc < 16; ++kc) af[kc] = *(const short8*)(ap + kc * 32);

    const int dd = (int)d_lds[(t << 5) + rowb];
    if (dd) {
      const short8 z8 = {0, 0, 0, 0, 0, 0, 0, 0};
#pragma unroll
      for (int kc = 0; kc < 16; ++kc) af[kc] = z8;
    }

    // stage next chunk (drained by this step's ending __syncthreads)
    if ((t & (GSTEPS - 1)) == 0 && t + GSTEPS < TT)
      stage_gin(((t >> 3) + 1) & 1, t + GSTEPS);

    // gin from LDS: 3x ds_read_b64 (4 consecutive cols per gate)
    const int sl = t & (GSTEPS - 1), bufc = (t >> 3) & 1;
    float gr[4], gz[4], gn[4];
    {
      const unsigned short* gl = &gin_lds[bufc][(size_t)sl * 3072
          + rowb * 32 + (wave >> 1) * 16 + quad * 4];
      unsigned long long w0 = *(const unsigned long long*)(gl);
      unsigned long long w1 = *(const unsigned long long*)(gl + 1024);
      unsigned long long w2 = *(const unsigned long long*)(gl + 2048);
#pragma unroll
      for (int i = 0; i < 4; ++i) {
        gr[i] = bf2f((unsigned short)(w0 >> (16 * i)));
        gz[i] = bf2f((unsigned short)(w1 >> (16 * i)));
        gn[i] = bf2f((unsigned short)(w2 >> (16 * i)));
      }
    }

    float4v a0 = {0.f, 0.f, 0.f, 0.f}, a1 = a0, a2 = a0;
#pragma unroll
    for (int kc = 0; kc < 16; ++kc) {
      a0 = __builtin_amdgcn_mfma_f32_16x16x32_bf16(bw[0][kc], af[kc], a0, 0, 0, 0);
      a1 = __builtin_amdgcn_mfma_f32_16x16x32_bf16(bw[1][kc], af[kc], a1, 0, 0, 0);
      a2 = __builtin_amdgcn_mfma_f32_16x16x32_bf16(bw[2][kc], af[kc], a2, 0, 0, 0);
    }

    unsigned short* ydst = ybuf + (size_t)t * 262144;
    float hv[4];
#pragma unroll
    for (int i = 0; i < 4; ++i) {
      float hold = dd ? 0.f : hprev[i];
      float r = 1.f / (1.f + __expf(-(a0[i] + gr[i])));
      float z = 1.f / (1.f + __expf(-(a1[i] + gz[i])));
      float npre = gn[i] + r * (a2[i] + bhn4[i]);
      float n = 1.f - 2.f / (1.f + __expf(2.f * npre));  // tanh, inf-safe
      hv[i] = (1.f - z) * n + z * hold;
      hprev[i] = hv[i];
    }
    {
      unsigned long long pk = (unsigned long long)f2bf(hv[0])
          | ((unsigned long long)f2bf(hv[1]) << 16)
          | ((unsigned long long)f2bf(hv[2]) << 32)
          | ((unsigned long long)f2bf(hv[3]) << 48);
      // write-through to coherence point (IC): next step's cross-XCD input
      store_u64_coh(ydst + (size_t)row * 512 + c0, pk);
    }
    if (t == TT - 1) {
      float4v o = {hv[0], hv[1], hv[2], hv[3]};
      *(float4v*)(outh + (size_t)row * 512 + c0) = o;
    }

    __syncthreads();  // s_waitcnt vmcnt(0) before s_barrier: h at IC
    if (tid == 0)
      store_u32_coh(&ready[(((size_t)rt * 130 + t + 1) * 16 + cc) * FSTRIDE], 1u);
  }
}

// ---------------- phase C: q = y @ w_out + b_out (N padded to 64) -----------

__global__ __launch_bounds__(256) void k_qout(
    const unsigned short* __restrict__ Yb, const unsigned short* __restrict__ Wt,
    const float* __restrict__ bout, float* __restrict__ Q) {
  __shared__ unsigned short As[8192];
  __shared__ unsigned short Bs[4096];
  const int tid = threadIdx.x, wave = tid >> 6, lane = tid & 63;
  const int quad = lane >> 4, l15 = lane & 15;
  const int m0 = blockIdx.x * 128;

  float4v acc[2][4];
#pragma unroll
  for (int a = 0; a < 2; ++a)
#pragma unroll
    for (int b = 0; b < 4; ++b) acc[a][b] = (float4v){0.f, 0.f, 0.f, 0.f};

  for (int k0 = 0; k0 < 512; k0 += 64) {
#pragma unroll
    for (int r = 0; r < 4; ++r) {
      int u = r * 256 + wave * 64 + lane;
      int ch = u >> 7, mm = u & 127;
      async16(&As[(size_t)(r * 256 + wave * 64) * 8],
              Yb + (size_t)(m0 + mm) * 512 + k0 + ch * 8);
    }
#pragma unroll
    for (int r = 0; r < 2; ++r) {
      int u = r * 256 + wave * 64 + lane;
      int ch = u >> 6, nn = u & 63;
      async16(&Bs[(size_t)(r * 256 + wave * 64) * 8],
              Wt + (size_t)nn * 512 + k0 + ch * 8);
    }
    __syncthreads();
#pragma unroll
    for (int kk = 0; kk < 2; ++kk) {
      short8 afr[2], bfr[4];
#pragma unroll
      for (int mi = 0; mi < 2; ++mi)
        afr[mi] = *(const short8*)
            &As[((kk * 4 + quad) * 128 + wave * 32 + mi * 16 + l15) * 8];
#pragma unroll
      for (int ni = 0; ni < 4; ++ni)
        bfr[ni] = *(const short8*)
            &Bs[((kk * 4 + quad) * 64 + ni * 16 + l15) * 8];
#pragma unroll
      for (int mi = 0; mi < 2; ++mi)
#pragma unroll
        for (int ni = 0; ni < 4; ++ni)
          acc[mi][ni] = __builtin_amdgcn_mfma_f32_16x16x32_bf16(
              afr[mi], bfr[ni], acc[mi][ni], 0, 0, 0);
    }
    __syncthreads();
  }
#pragma unroll
  for (int mi = 0; mi < 2; ++mi)
#pragma unroll
    for (int ni = 0; ni < 4; ++ni)
#pragma unroll
      for (int i = 0; i < 4; ++i) {
        int row = m0 + wave * 32 + mi * 16 + quad * 4 + i;
        int colq = ni * 16 + l15;
        if (colq < AD) Q[(size_t)row * AD + colq] = acc[mi][ni][i] + bout[colq];
      }
}

// ---------------- launch ----------------------------------------------------

extern "C" void kernel_launch(void* const* d_in, const int* in_sizes, int n_in,
                              void* d_out, int out_size, void* d_ws,
                              size_t ws_size, hipStream_t stream) {
  const float* hidden = (const float*)d_in[0];
  const float* obs = (const float*)d_in[1];
  const void* dones = d_in[2];
  const int* acts = (const int*)d_in[3];
  const float* w0 = (const float*)d_in[4];
  const float* b0 = (const float*)d_in[5];
  const float* ln0s = (const float*)d_in[6];
  const float* ln0b = (const float*)d_in[7];
  const float* w1 = (const float*)d_in[8];
  const float* b1 = (const float*)d_in[9];
  const float* ln1s = (const float*)d_in[10];
  const float* ln1b = (const float*)d_in[11];
  const float* wir = (const float*)d_in[12];
  const float* bir = (const float*)d_in[13];
  const float* wiz = (const float*)d_in[14];
  const float* biz = (const float*)d_in[15];
  const float* win = (const float*)d_in[16];
  const float* bin = (const float*)d_in[17];
  const float* whr = (const float*)d_in[18];
  const float* whz = (const float*)d_in[19];
  const float* whn = (const float*)d_in[20];
  const float* bhn = (const float*)d_in[21];
  const float* wout = (const float*)d_in[22];
  const float* bout = (const float*)d_in[23];

  char* ws = (char*)d_ws;
  unsigned short* bufA = (unsigned short*)(ws);                   // 64MB: x2 -> [ready]
  unsigned short* bufB = (unsigned short*)(ws + 67108864ULL);     // 64MB: x1 -> y/h
  unsigned short* gin = (unsigned short*)(ws + 134217728ULL);     // 192MB (scan-blocked)
  char* D = ws + 134217728ULL + 201326592ULL;
  unsigned short* W0at = (unsigned short*)(D);                    // 512KB
  unsigned short* W1t = (unsigned short*)(D + 524288);            // 512KB
  unsigned short* Wit = (unsigned short*)(D + 1048576);           // 1.5MB
  unsigned short* Whf = (unsigned short*)(D + 2621440);           // 1.5MB
  unsigned short* WoutT = (unsigned short*)(D + 4194304);         // 64KB
  unsigned short* w0act = (unsigned short*)(D + 4259840);         // 32KB
  float* gib = (float*)(D + 4292608);                             // 8KB
  unsigned short* hbuf = (unsigned short*)(D + 4300800);          // 512KB init h
  unsigned int* flag = (unsigned int*)(D + 4825088);              // 4B dones-dtype
  unsigned int* ready = (unsigned int*)ws;                        // 4.26MB in bufA

  (void)in_sizes; (void)n_in; (void)out_size; (void)ws_size;

  // all weight/misc prep + self-contained dones-dtype probe: ONE kernel
  k_prep<<<9216, 256, 0, stream>>>(w0, w1, wir, wiz, win, whr, whz, whn,
                                   bir, biz, bin, wout, hidden,
                                   (const int*)dones, W0at, W1t, Wit, Whf,
                                   w0act, gib, WoutT, hbuf, flag);
  // fused encoder: GEMM+bias(+gather)+LN+ReLU per layer; obs fp32 direct
  k_enc<0><<<512, 512, 0, stream>>>((const unsigned short*)obs, W0at, bufB,
                                    b0, ln0s, ln0b, w0act, acts);
  k_enc<1><<<512, 512, 0, stream>>>(bufB, W1t, bufA, b1, ln1s, ln1b,
                                    nullptr, nullptr);
  // GRU input projections (biases fused), written scan-blocked; 1 gate per y
  k_enc<2><<<dim3(512, 3), 512, 0, stream>>>(bufA, Wit, gin, gib, nullptr,
                                             nullptr, nullptr, nullptr);
  // bufA is now dead: zero the spread flag array there
  k_zero<<<1041, 256, 0, stream>>>(ready);
  // sequential scan; writes new_hidden to d_out[0:262144] and y/h to bufB
  k_gru<<<256, 256, 0, stream>>>(Whf, gin, bhn, (const int*)dones,
                                 (const unsigned char*)dones, flag, hbuf, bufB,
                                 (float*)d_out, ready);
  // output head -> d_out[262144:]
  k_qout<<<512, 256, 0, stream>>>(bufB, WoutT, bout, (float*)d_out + 262144);
}